// Round 1
// baseline (2618.558 us; speedup 1.0000x reference)
//
#include <hip/hip_runtime.h>

#define NA 50000
#define NB 50000
#define CDIM 128
#define EDGES 800000
#define SS 8
#define INDIM 64
#define HDIM 64
#define NBASES 8

// ---------------------------------------------------------------------------
// Workspace layout (float offsets):
//   0         msg_ab   [NB*128]
//   6400000   msg_ba   [NA*128]
//   12800000  msg_aa   [NA*128]
//   19200000  cnt_ab   [50000]
//   19250000  cnt_ba   [50000]
//   19300000  cnt_aa   [50000]
//   19350000  xa_buf   [NA*128]   (layer-0 output a)
//   25750000  xb_buf   [NB*128]   (layer-0 output b)
//   32150000  W        [6*128*128]  (l*3+t, t:0=ab,1=ba,2=aa; row-major [j][k])
//   32248304  coeffs   [3*8]
// total ~129 MB
// ---------------------------------------------------------------------------

// Schema GCN + coefficient computation. One block, 512 threads (8 rows x 64 cols).
__global__ __launch_bounds__(512) void schema_kernel(
    const float* __restrict__ schema_x, const int* __restrict__ sei,
    const float* __restrict__ preW, const float* __restrict__ preb,
    const float* __restrict__ gcnW, const float* __restrict__ gcnb,
    const float* __restrict__ coW, const float* __restrict__ cob,
    float* __restrict__ out_sf, float* __restrict__ out_ori,
    float* __restrict__ coeffs)
{
    __shared__ float h[SS][HDIM];
    __shared__ float xw[SS][HDIM];
    __shared__ float sf[SS][HDIM];
    __shared__ float deg[SS];
    __shared__ float nrm[32];
    __shared__ int es[32], ed[32];

    int t = threadIdx.x;
    int i = t >> 6, j = t & 63;

    // h = schema_x @ preW.T + preb  (this is also 'ori')
    float acc = preb[j];
    for (int k = 0; k < INDIM; k++) acc += schema_x[i * INDIM + k] * preW[j * INDIM + k];
    h[i][j] = acc;
    out_ori[i * HDIM + j] = acc;
    if (t < SS) deg[t] = 0.0f;
    __syncthreads();

    // edge list with self loops; degree over dst
    if (t < 32) {
        int s, d;
        if (t < 24) { s = sei[t]; d = sei[24 + t]; }
        else        { s = t - 24; d = t - 24; }
        es[t] = s; ed[t] = d;
        atomicAdd(&deg[d], 1.0f);
    }
    __syncthreads();
    if (t < 32) {
        nrm[t] = rsqrtf(fmaxf(deg[es[t]], 1e-12f)) * rsqrtf(fmaxf(deg[ed[t]], 1e-12f));
    }
    // xw = h @ gcnW.T
    float a2 = 0.0f;
    for (int k = 0; k < HDIM; k++) a2 += h[i][k] * gcnW[j * HDIM + k];
    xw[i][j] = a2;
    __syncthreads();

    // out[d] = sum_e xw[src]*norm  + b ; relu -> sf
    float o = gcnb[j];
    for (int e = 0; e < 32; e++) {
        if (ed[e] == i) o += xw[es[e]][j] * nrm[e];
    }
    float s = fmaxf(o, 0.0f);
    sf[i][j] = s;
    out_sf[i * HDIM + j] = s;
    __syncthreads();

    // coeffs[type][i] = concat(sf[srow], sf[drow]) . coW[i] + cob[i]
    if (t < 24) {
        int ty = t >> 3, ii = t & 7;
        int srow = (ty == 1) ? 1 : 0;
        int drow = (ty == 0) ? 1 : 0;
        float a = cob[ii];
        for (int k = 0; k < HDIM; k++) a += sf[srow][k] * coW[ii * (2 * HDIM) + k];
        for (int k = 0; k < HDIM; k++) a += sf[drow][k] * coW[ii * (2 * HDIM) + HDIM + k];
        coeffs[ty * 8 + ii] = a;
    }
}

// W[l][t][j][k] = sum_i coeffs[t][i] * bases[l][i][j][k]   (6*16384 outputs)
__global__ __launch_bounds__(256) void build_w_kernel(
    const float* __restrict__ bases, const float* __restrict__ coeffs,
    float* __restrict__ W)
{
    int idx = blockIdx.x * blockDim.x + threadIdx.x;   // < 6*16384
    int lt = idx >> 14;
    int jk = idx & 16383;
    int l = lt / 3, ty = lt % 3;
    float acc = 0.0f;
#pragma unroll
    for (int i = 0; i < NBASES; i++)
        acc += coeffs[ty * 8 + i] * bases[((size_t)(l * NBASES + i) << 14) + jk];
    W[idx] = acc;
}

// Edge scatter: 32 lanes per edge, 4 coalesced 128B passes of fp32 atomics.
__global__ __launch_bounds__(256) void scatter_kernel(
    const float* __restrict__ x, const int* __restrict__ esrc, const int* __restrict__ edst,
    float* __restrict__ msg, float* __restrict__ cnt, int do_cnt)
{
    int g = blockIdx.x * blockDim.x + threadIdx.x;
    int e = g >> 5, lane = g & 31;
    if (e >= EDGES) return;
    int sN = esrc[e], dN = edst[e];
    const float* xs = x + (size_t)sN * CDIM;
    float* md = msg + (size_t)dN * CDIM;
#pragma unroll
    for (int p = 0; p < 4; p++) {
        int c = lane + (p << 5);
        atomicAdd(&md[c], xs[c]);
    }
    if (do_cnt && lane == 0) atomicAdd(&cnt[dN], 1.0f);
}

// Fused (mean + x) @ W.T + bias -> LayerNorm -> ReLU for the 'b' side.
// 128 threads (one per output col), 8 rows per block.
__global__ __launch_bounds__(128) void fuse_b_kernel(
    const float* __restrict__ msg, const float* __restrict__ cnt,
    const float* __restrict__ xcur, const float* __restrict__ W,
    const float* __restrict__ bias, const float* __restrict__ lnw,
    const float* __restrict__ lnb, float* __restrict__ xnext)
{
    const int R = 8;
    __shared__ __align__(16) float U[R][CDIM];
    __shared__ float red[2][2];
    int t = threadIdx.x;
    int base = blockIdx.x * R;

    for (int r = 0; r < R; r++) {
        int row = base + r;
        float inv = 1.0f / fmaxf(cnt[row], 1.0f);
        U[r][t] = msg[(size_t)row * CDIM + t] * inv + xcur[(size_t)row * CDIM + t];
    }
    __syncthreads();

    float acc[R];
    float b = bias[t];
#pragma unroll
    for (int r = 0; r < R; r++) acc[r] = b;

    const float4* Wr = (const float4*)(W + (size_t)t * CDIM);
    for (int k4 = 0; k4 < 32; k4++) {
        float4 w = Wr[k4];
#pragma unroll
        for (int r = 0; r < R; r++) {
            float4 u = *(const float4*)&U[r][k4 * 4];
            acc[r] += u.x * w.x + u.y * w.y + u.z * w.z + u.w * w.w;
        }
    }

    float lw = lnw[t], lb = lnb[t];
    int wid = t >> 6, lane = t & 63;
    for (int r = 0; r < R; r++) {
        float v = acc[r];
        float s = v, s2 = v * v;
        for (int off = 32; off > 0; off >>= 1) {
            s += __shfl_down(s, off, 64);
            s2 += __shfl_down(s2, off, 64);
        }
        if (lane == 0) { red[wid][0] = s; red[wid][1] = s2; }
        __syncthreads();
        float tot = red[0][0] + red[1][0];
        float tot2 = red[0][1] + red[1][1];
        float mu = tot * (1.0f / CDIM);
        float var = tot2 * (1.0f / CDIM) - mu * mu;
        float rs = rsqrtf(var + 1e-5f);
        float o = (v - mu) * rs * lw + lb;
        xnext[(size_t)(base + r) * CDIM + t] = fmaxf(o, 0.0f);
        __syncthreads();
    }
}

// Fused a-side: (mean_ba + x)@Wba.T + (mean_aa + x)@Waa.T + b1 + b2 -> LN -> ReLU
__global__ __launch_bounds__(128) void fuse_a_kernel(
    const float* __restrict__ msg1, const float* __restrict__ cnt1,
    const float* __restrict__ msg2, const float* __restrict__ cnt2,
    const float* __restrict__ xcur,
    const float* __restrict__ W1, const float* __restrict__ W2,
    const float* __restrict__ bias1, const float* __restrict__ bias2,
    const float* __restrict__ lnw, const float* __restrict__ lnb,
    float* __restrict__ xnext)
{
    const int R = 8;
    __shared__ __align__(16) float U[R][CDIM];
    __shared__ __align__(16) float V[R][CDIM];
    __shared__ float red[2][2];
    int t = threadIdx.x;
    int base = blockIdx.x * R;

    for (int r = 0; r < R; r++) {
        int row = base + r;
        float xv = xcur[(size_t)row * CDIM + t];
        float inv1 = 1.0f / fmaxf(cnt1[row], 1.0f);
        float inv2 = 1.0f / fmaxf(cnt2[row], 1.0f);
        U[r][t] = msg1[(size_t)row * CDIM + t] * inv1 + xv;
        V[r][t] = msg2[(size_t)row * CDIM + t] * inv2 + xv;
    }
    __syncthreads();

    float acc[R];
    float b = bias1[t] + bias2[t];
#pragma unroll
    for (int r = 0; r < R; r++) acc[r] = b;

    const float4* W1r = (const float4*)(W1 + (size_t)t * CDIM);
    const float4* W2r = (const float4*)(W2 + (size_t)t * CDIM);
    for (int k4 = 0; k4 < 32; k4++) {
        float4 w1 = W1r[k4];
        float4 w2 = W2r[k4];
#pragma unroll
        for (int r = 0; r < R; r++) {
            float4 u = *(const float4*)&U[r][k4 * 4];
            float4 v = *(const float4*)&V[r][k4 * 4];
            acc[r] += u.x * w1.x + u.y * w1.y + u.z * w1.z + u.w * w1.w
                    + v.x * w2.x + v.y * w2.y + v.z * w2.z + v.w * w2.w;
        }
    }

    float lw = lnw[t], lb = lnb[t];
    int wid = t >> 6, lane = t & 63;
    for (int r = 0; r < R; r++) {
        float v = acc[r];
        float s = v, s2 = v * v;
        for (int off = 32; off > 0; off >>= 1) {
            s += __shfl_down(s, off, 64);
            s2 += __shfl_down(s2, off, 64);
        }
        if (lane == 0) { red[wid][0] = s; red[wid][1] = s2; }
        __syncthreads();
        float tot = red[0][0] + red[1][0];
        float tot2 = red[0][1] + red[1][1];
        float mu = tot * (1.0f / CDIM);
        float var = tot2 * (1.0f / CDIM) - mu * mu;
        float rs = rsqrtf(var + 1e-5f);
        float o = (v - mu) * rs * lw + lb;
        xnext[(size_t)(base + r) * CDIM + t] = fmaxf(o, 0.0f);
        __syncthreads();
    }
}

extern "C" void kernel_launch(void* const* d_in, const int* in_sizes, int n_in,
                              void* d_out, int out_size, void* d_ws, size_t ws_size,
                              hipStream_t stream)
{
    const float* x_a      = (const float*)d_in[0];
    const float* x_b      = (const float*)d_in[1];
    const float* schema_x = (const float*)d_in[2];
    const int*   e_ab     = (const int*)d_in[3];
    const int*   e_ba     = (const int*)d_in[4];
    const int*   e_aa     = (const int*)d_in[5];
    const int*   sei      = (const int*)d_in[6];
    const float* preW     = (const float*)d_in[7];
    const float* preb     = (const float*)d_in[8];
    const float* gcnW     = (const float*)d_in[9];
    const float* gcnb     = (const float*)d_in[10];
    const float* coW      = (const float*)d_in[11];
    const float* cob      = (const float*)d_in[12];
    const float* bases    = (const float*)d_in[13];
    const float* sbias    = (const float*)d_in[14];
    const float* lnw      = (const float*)d_in[15];
    const float* lnb      = (const float*)d_in[16];

    float* out    = (float*)d_out;
    float* out_xa = out;
    float* out_xb = out + 6400000;
    float* out_sf = out + 12800000;
    float* out_ori = out + 12800512;

    float* ws     = (float*)d_ws;
    float* msg_ab = ws;
    float* msg_ba = ws + 6400000;
    float* msg_aa = ws + 12800000;
    float* cnt_ab = ws + 19200000;
    float* cnt_ba = ws + 19250000;
    float* cnt_aa = ws + 19300000;
    float* xa_buf = ws + 19350000;
    float* xb_buf = ws + 25750000;
    float* Wbuf   = ws + 32150000;
    float* coeffs = ws + 32248304;

    schema_kernel<<<1, 512, 0, stream>>>(schema_x, sei, preW, preb, gcnW, gcnb,
                                         coW, cob, out_sf, out_ori, coeffs);
    build_w_kernel<<<384, 256, 0, stream>>>(bases, coeffs, Wbuf);

    const int sgrid = (EDGES * 32) / 256;   // 100000 blocks
    for (int l = 0; l < 2; l++) {
        // zero msg (and cnt in layer 0; cnt is layer-invariant, reused in layer 1)
        size_t zfloats = (l == 0) ? 19350000ull : 19200000ull;
        hipMemsetAsync(ws, 0, zfloats * sizeof(float), stream);

        const float* xa_cur = (l == 0) ? x_a : xa_buf;
        const float* xb_cur = (l == 0) ? x_b : xb_buf;

        scatter_kernel<<<sgrid, 256, 0, stream>>>(xa_cur, e_ab, e_ab + EDGES, msg_ab, cnt_ab, l == 0);
        scatter_kernel<<<sgrid, 256, 0, stream>>>(xb_cur, e_ba, e_ba + EDGES, msg_ba, cnt_ba, l == 0);
        scatter_kernel<<<sgrid, 256, 0, stream>>>(xa_cur, e_aa, e_aa + EDGES, msg_aa, cnt_aa, l == 0);

        const float* Wab = Wbuf + (size_t)(l * 3 + 0) * 16384;
        const float* Wba = Wbuf + (size_t)(l * 3 + 1) * 16384;
        const float* Waa = Wbuf + (size_t)(l * 3 + 2) * 16384;
        float* xa_nxt = (l == 0) ? xa_buf : out_xa;
        float* xb_nxt = (l == 0) ? xb_buf : out_xb;

        fuse_b_kernel<<<NB / 8, 128, 0, stream>>>(
            msg_ab, cnt_ab, xb_cur, Wab,
            sbias + (size_t)(l * 3 + 0) * 128,
            lnw + (size_t)(l * 2 + 1) * 128, lnb + (size_t)(l * 2 + 1) * 128,
            xb_nxt);
        fuse_a_kernel<<<NA / 8, 128, 0, stream>>>(
            msg_ba, cnt_ba, msg_aa, cnt_aa, xa_cur, Wba, Waa,
            sbias + (size_t)(l * 3 + 1) * 128, sbias + (size_t)(l * 3 + 2) * 128,
            lnw + (size_t)(l * 2 + 0) * 128, lnb + (size_t)(l * 2 + 0) * 128,
            xa_nxt);
    }
}

// Round 2
// 1311.571 us; speedup vs baseline: 1.9965x; 1.9965x over previous
//
#include <hip/hip_runtime.h>

#define NA 50000
#define NB 50000
#define NN 50000
#define CDIM 128
#define EDGES 800000
#define SS 8
#define INDIM 64
#define HDIM 64
#define NBASES 8

// ---------------------------------------------------------------------------
// Workspace layout (4-byte element offsets):
//   0         col      [3*E]      int   (ab, ba, aa buckets, dst-sorted src ids)
//   2400000   rowptr   [3*(NN+1)] int
//   2550003   pos      [3*NN]     int   (fill cursors)
//   2700003   hist     [3*NN]     int
//   2850016   xa_buf   [NA*128]   float (layer-0 output a)
//   9250016   xb_buf   [NB*128]   float
//   15650016  W        [6*128*128] float
//   15748320  coeffs   [3*8]      float
// total ~63 MB
// ---------------------------------------------------------------------------

// Schema GCN + coefficient computation. One block, 512 threads (8 rows x 64 cols).
__global__ __launch_bounds__(512) void schema_kernel(
    const float* __restrict__ schema_x, const int* __restrict__ sei,
    const float* __restrict__ preW, const float* __restrict__ preb,
    const float* __restrict__ gcnW, const float* __restrict__ gcnb,
    const float* __restrict__ coW, const float* __restrict__ cob,
    float* __restrict__ out_sf, float* __restrict__ out_ori,
    float* __restrict__ coeffs)
{
    __shared__ float h[SS][HDIM];
    __shared__ float xw[SS][HDIM];
    __shared__ float sf[SS][HDIM];
    __shared__ float deg[SS];
    __shared__ float nrm[32];
    __shared__ int es[32], ed[32];

    int t = threadIdx.x;
    int i = t >> 6, j = t & 63;

    float acc = preb[j];
    for (int k = 0; k < INDIM; k++) acc += schema_x[i * INDIM + k] * preW[j * INDIM + k];
    h[i][j] = acc;
    out_ori[i * HDIM + j] = acc;
    if (t < SS) deg[t] = 0.0f;
    __syncthreads();

    if (t < 32) {
        int s, d;
        if (t < 24) { s = sei[t]; d = sei[24 + t]; }
        else        { s = t - 24; d = t - 24; }
        es[t] = s; ed[t] = d;
        atomicAdd(&deg[d], 1.0f);
    }
    __syncthreads();
    if (t < 32) {
        nrm[t] = rsqrtf(fmaxf(deg[es[t]], 1e-12f)) * rsqrtf(fmaxf(deg[ed[t]], 1e-12f));
    }
    float a2 = 0.0f;
    for (int k = 0; k < HDIM; k++) a2 += h[i][k] * gcnW[j * HDIM + k];
    xw[i][j] = a2;
    __syncthreads();

    float o = gcnb[j];
    for (int e = 0; e < 32; e++) {
        if (ed[e] == i) o += xw[es[e]][j] * nrm[e];
    }
    float s = fmaxf(o, 0.0f);
    sf[i][j] = s;
    out_sf[i * HDIM + j] = s;
    __syncthreads();

    if (t < 24) {
        int ty = t >> 3, ii = t & 7;
        int srow = (ty == 1) ? 1 : 0;
        int drow = (ty == 0) ? 1 : 0;
        float a = cob[ii];
        for (int k = 0; k < HDIM; k++) a += sf[srow][k] * coW[ii * (2 * HDIM) + k];
        for (int k = 0; k < HDIM; k++) a += sf[drow][k] * coW[ii * (2 * HDIM) + HDIM + k];
        coeffs[ty * 8 + ii] = a;
    }
}

__global__ __launch_bounds__(256) void build_w_kernel(
    const float* __restrict__ bases, const float* __restrict__ coeffs,
    float* __restrict__ W)
{
    int idx = blockIdx.x * blockDim.x + threadIdx.x;
    int lt = idx >> 14;
    int jk = idx & 16383;
    int l = lt / 3, ty = lt % 3;
    float acc = 0.0f;
#pragma unroll
    for (int i = 0; i < NBASES; i++)
        acc += coeffs[ty * 8 + i] * bases[((size_t)(l * NBASES + i) << 14) + jk];
    W[idx] = acc;
}

// ---------------- CSR build (once per launch; edges are layer-invariant) ----

__global__ __launch_bounds__(256) void hist_kernel(
    const int* __restrict__ ab, const int* __restrict__ ba,
    const int* __restrict__ aa, int* __restrict__ hist)
{
    int e = blockIdx.x * 256 + threadIdx.x;
    int ty = blockIdx.y;
    if (e >= EDGES) return;
    const int* ei = (ty == 0) ? ab : (ty == 1) ? ba : aa;
    atomicAdd(&hist[ty * NN + ei[EDGES + e]], 1);
}

// One block of 1024 per edge type: exclusive scan of hist -> rowptr, pos.
__global__ __launch_bounds__(1024) void scan_kernel(
    const int* __restrict__ hist, int* __restrict__ rowptr, int* __restrict__ pos)
{
    const int CH = 49;  // 1024*49 = 50176 >= 50000
    int ty = blockIdx.x;
    const int* h = hist + ty * NN;
    int* rp = rowptr + ty * (NN + 1);
    int* ps = pos + ty * NN;

    __shared__ int sbuf[1024];
    int t = threadIdx.x;
    int start = t * CH;
    int end = min(start + CH, NN);

    int sum = 0;
    for (int i = start; i < end; i++) sum += h[i];
    sbuf[t] = sum;
    __syncthreads();
    for (int off = 1; off < 1024; off <<= 1) {
        int v = (t >= off) ? sbuf[t - off] : 0;
        __syncthreads();
        sbuf[t] += v;
        __syncthreads();
    }
    int run = sbuf[t] - sum;   // exclusive prefix
    for (int i = start; i < end; i++) {
        rp[i] = run; ps[i] = run;
        run += h[i];
    }
    if (t == 1023) rp[NN] = run;   // == EDGES
}

__global__ __launch_bounds__(256) void fill_kernel(
    const int* __restrict__ ab, const int* __restrict__ ba,
    const int* __restrict__ aa, int* __restrict__ pos, int* __restrict__ col)
{
    int e = blockIdx.x * 256 + threadIdx.x;
    int ty = blockIdx.y;
    if (e >= EDGES) return;
    const int* ei = (ty == 0) ? ab : (ty == 1) ? ba : aa;
    int src = ei[e], dst = ei[EDGES + e];
    int slot = atomicAdd(&pos[ty * NN + dst], 1);
    col[(size_t)ty * EDGES + slot] = src;
}

// ---------------- fused gather + (mean + x)@W^T + bias -> LN -> ReLU --------

__device__ __forceinline__ float gather_row(
    const float* __restrict__ xsrc, const int* __restrict__ col,
    int s, int e, int t)
{
    float g = 0.0f;
    int i = s;
    for (; i + 4 <= e; i += 4) {
        int c0 = col[i], c1 = col[i + 1], c2 = col[i + 2], c3 = col[i + 3];
        float v0 = xsrc[(size_t)c0 * CDIM + t];
        float v1 = xsrc[(size_t)c1 * CDIM + t];
        float v2 = xsrc[(size_t)c2 * CDIM + t];
        float v3 = xsrc[(size_t)c3 * CDIM + t];
        g += (v0 + v1) + (v2 + v3);
    }
    for (; i < e; i++) g += xsrc[(size_t)col[i] * CDIM + t];
    return g;
}

// b-side: mean(x_a[in-edges]) + x_b, @W^T + bias -> LN -> ReLU
__global__ __launch_bounds__(128) void fuse_b_kernel(
    const float* __restrict__ xsrc, const float* __restrict__ xdst,
    const int* __restrict__ rowptr, const int* __restrict__ col,
    const float* __restrict__ W, const float* __restrict__ bias,
    const float* __restrict__ lnw, const float* __restrict__ lnb,
    float* __restrict__ xnext)
{
    const int R = 8;
    __shared__ __align__(16) float U[R][CDIM];
    __shared__ float red[2][2];
    int t = threadIdx.x;
    int base = blockIdx.x * R;

    for (int r = 0; r < R; r++) {
        int row = base + r;
        int s = rowptr[row], e = rowptr[row + 1];
        float g = gather_row(xsrc, col, s, e, t);
        float inv = 1.0f / (float)max(e - s, 1);
        U[r][t] = g * inv + xdst[(size_t)row * CDIM + t];
    }
    __syncthreads();

    float acc[R];
    float b = bias[t];
#pragma unroll
    for (int r = 0; r < R; r++) acc[r] = b;

    const float4* Wr = (const float4*)(W + (size_t)t * CDIM);
    for (int k4 = 0; k4 < 32; k4++) {
        float4 w = Wr[k4];
#pragma unroll
        for (int r = 0; r < R; r++) {
            float4 u = *(const float4*)&U[r][k4 * 4];
            acc[r] += u.x * w.x + u.y * w.y + u.z * w.z + u.w * w.w;
        }
    }

    float lw = lnw[t], lb = lnb[t];
    int wid = t >> 6, lane = t & 63;
    for (int r = 0; r < R; r++) {
        float v = acc[r];
        float s = v, s2 = v * v;
        for (int off = 32; off > 0; off >>= 1) {
            s += __shfl_down(s, off, 64);
            s2 += __shfl_down(s2, off, 64);
        }
        if (lane == 0) { red[wid][0] = s; red[wid][1] = s2; }
        __syncthreads();
        float tot = red[0][0] + red[1][0];
        float tot2 = red[0][1] + red[1][1];
        float mu = tot * (1.0f / CDIM);
        float var = tot2 * (1.0f / CDIM) - mu * mu;
        float rs = rsqrtf(var + 1e-5f);
        float o = (v - mu) * rs * lw + lb;
        xnext[(size_t)(base + r) * CDIM + t] = fmaxf(o, 0.0f);
        __syncthreads();
    }
}

// a-side: (mean_ba(x_b)+x_a)@W1^T + (mean_aa(x_a)+x_a)@W2^T + b1+b2 -> LN -> ReLU
__global__ __launch_bounds__(128) void fuse_a_kernel(
    const float* __restrict__ xsrc1, const int* __restrict__ rowptr1, const int* __restrict__ col1,
    const float* __restrict__ xsrc2, const int* __restrict__ rowptr2, const int* __restrict__ col2,
    const float* __restrict__ xdst,
    const float* __restrict__ W1, const float* __restrict__ W2,
    const float* __restrict__ bias1, const float* __restrict__ bias2,
    const float* __restrict__ lnw, const float* __restrict__ lnb,
    float* __restrict__ xnext)
{
    const int R = 8;
    __shared__ __align__(16) float U[R][CDIM];
    __shared__ __align__(16) float V[R][CDIM];
    __shared__ float red[2][2];
    int t = threadIdx.x;
    int base = blockIdx.x * R;

    for (int r = 0; r < R; r++) {
        int row = base + r;
        float xv = xdst[(size_t)row * CDIM + t];
        int s1 = rowptr1[row], e1 = rowptr1[row + 1];
        float g1 = gather_row(xsrc1, col1, s1, e1, t);
        U[r][t] = g1 * (1.0f / (float)max(e1 - s1, 1)) + xv;
        int s2 = rowptr2[row], e2 = rowptr2[row + 1];
        float g2 = gather_row(xsrc2, col2, s2, e2, t);
        V[r][t] = g2 * (1.0f / (float)max(e2 - s2, 1)) + xv;
    }
    __syncthreads();

    float acc[R];
    float b = bias1[t] + bias2[t];
#pragma unroll
    for (int r = 0; r < R; r++) acc[r] = b;

    const float4* W1r = (const float4*)(W1 + (size_t)t * CDIM);
    const float4* W2r = (const float4*)(W2 + (size_t)t * CDIM);
    for (int k4 = 0; k4 < 32; k4++) {
        float4 w1 = W1r[k4];
        float4 w2 = W2r[k4];
#pragma unroll
        for (int r = 0; r < R; r++) {
            float4 u = *(const float4*)&U[r][k4 * 4];
            float4 v = *(const float4*)&V[r][k4 * 4];
            acc[r] += u.x * w1.x + u.y * w1.y + u.z * w1.z + u.w * w1.w
                    + v.x * w2.x + v.y * w2.y + v.z * w2.z + v.w * w2.w;
        }
    }

    float lw = lnw[t], lb = lnb[t];
    int wid = t >> 6, lane = t & 63;
    for (int r = 0; r < R; r++) {
        float v = acc[r];
        float s = v, s2 = v * v;
        for (int off = 32; off > 0; off >>= 1) {
            s += __shfl_down(s, off, 64);
            s2 += __shfl_down(s2, off, 64);
        }
        if (lane == 0) { red[wid][0] = s; red[wid][1] = s2; }
        __syncthreads();
        float tot = red[0][0] + red[1][0];
        float tot2 = red[0][1] + red[1][1];
        float mu = tot * (1.0f / CDIM);
        float var = tot2 * (1.0f / CDIM) - mu * mu;
        float rs = rsqrtf(var + 1e-5f);
        float o = (v - mu) * rs * lw + lb;
        xnext[(size_t)(base + r) * CDIM + t] = fmaxf(o, 0.0f);
        __syncthreads();
    }
}

extern "C" void kernel_launch(void* const* d_in, const int* in_sizes, int n_in,
                              void* d_out, int out_size, void* d_ws, size_t ws_size,
                              hipStream_t stream)
{
    const float* x_a      = (const float*)d_in[0];
    const float* x_b      = (const float*)d_in[1];
    const float* schema_x = (const float*)d_in[2];
    const int*   e_ab     = (const int*)d_in[3];
    const int*   e_ba     = (const int*)d_in[4];
    const int*   e_aa     = (const int*)d_in[5];
    const int*   sei      = (const int*)d_in[6];
    const float* preW     = (const float*)d_in[7];
    const float* preb     = (const float*)d_in[8];
    const float* gcnW     = (const float*)d_in[9];
    const float* gcnb     = (const float*)d_in[10];
    const float* coW      = (const float*)d_in[11];
    const float* cob      = (const float*)d_in[12];
    const float* bases    = (const float*)d_in[13];
    const float* sbias    = (const float*)d_in[14];
    const float* lnw      = (const float*)d_in[15];
    const float* lnb      = (const float*)d_in[16];

    float* out     = (float*)d_out;
    float* out_xa  = out;
    float* out_xb  = out + 6400000;
    float* out_sf  = out + 12800000;
    float* out_ori = out + 12800512;

    float* ws = (float*)d_ws;
    int*   col    = (int*)ws;                 // [3*E]
    int*   rowptr = (int*)(ws + 2400000);     // [3*(NN+1)]
    int*   pos    = (int*)(ws + 2550003);     // [3*NN]
    int*   hist   = (int*)(ws + 2700003);     // [3*NN]
    float* xa_buf = ws + 2850016;
    float* xb_buf = ws + 9250016;
    float* Wbuf   = ws + 15650016;
    float* coeffs = ws + 15748320;

    // schema + dynamic weights
    schema_kernel<<<1, 512, 0, stream>>>(schema_x, sei, preW, preb, gcnW, gcnb,
                                         coW, cob, out_sf, out_ori, coeffs);
    build_w_kernel<<<384, 256, 0, stream>>>(bases, coeffs, Wbuf);

    // CSR build (layer-invariant)
    hipMemsetAsync(hist, 0, 3 * NN * sizeof(int), stream);
    dim3 egrid(EDGES / 256, 3);
    hist_kernel<<<egrid, 256, 0, stream>>>(e_ab, e_ba, e_aa, hist);
    scan_kernel<<<3, 1024, 0, stream>>>(hist, rowptr, pos);
    fill_kernel<<<egrid, 256, 0, stream>>>(e_ab, e_ba, e_aa, pos, col);

    const int* rp_ab = rowptr;
    const int* rp_ba = rowptr + (NN + 1);
    const int* rp_aa = rowptr + 2 * (NN + 1);
    const int* col_ab = col;
    const int* col_ba = col + EDGES;
    const int* col_aa = col + 2 * EDGES;

    for (int l = 0; l < 2; l++) {
        const float* xa_cur = (l == 0) ? x_a : xa_buf;
        const float* xb_cur = (l == 0) ? x_b : xb_buf;
        const float* Wab = Wbuf + (size_t)(l * 3 + 0) * 16384;
        const float* Wba = Wbuf + (size_t)(l * 3 + 1) * 16384;
        const float* Waa = Wbuf + (size_t)(l * 3 + 2) * 16384;
        float* xa_nxt = (l == 0) ? xa_buf : out_xa;
        float* xb_nxt = (l == 0) ? xb_buf : out_xb;

        fuse_b_kernel<<<NB / 8, 128, 0, stream>>>(
            xa_cur, xb_cur, rp_ab, col_ab, Wab,
            sbias + (size_t)(l * 3 + 0) * 128,
            lnw + (size_t)(l * 2 + 1) * 128, lnb + (size_t)(l * 2 + 1) * 128,
            xb_nxt);
        fuse_a_kernel<<<NA / 8, 128, 0, stream>>>(
            xb_cur, rp_ba, col_ba, xa_cur, rp_aa, col_aa, xa_cur,
            Wba, Waa,
            sbias + (size_t)(l * 3 + 1) * 128, sbias + (size_t)(l * 3 + 2) * 128,
            lnw + (size_t)(l * 2 + 0) * 128, lnb + (size_t)(l * 2 + 0) * 128,
            xa_nxt);
    }
}

// Round 3
// 1261.461 us; speedup vs baseline: 2.0758x; 1.0397x over previous
//
#include <hip/hip_runtime.h>

#define NA 50000
#define NB 50000
#define NN 50000
#define CDIM 128
#define EDGES 800000
#define SS 8
#define INDIM 64
#define HDIM 64
#define NBASES 8

// ---------------------------------------------------------------------------
// Workspace layout (4-byte element offsets):
//   0         col      [3*E]      int   (ab, ba, aa buckets, dst-sorted src ids)
//   2400000   rowptr   [3*(NN+1)] int
//   2550003   pos      [3*NN]     int   (fill cursors)
//   2700003   hist     [3*NN]     int
//   2850016   xa_buf   [NA*128]   float (layer-0 output a)
//   9250016   xb_buf   [NB*128]   float
//   15650016  W        [6*128*128] float
//   15748320  coeffs   [3*8]      float
// total ~63 MB
// ---------------------------------------------------------------------------

// Schema GCN + coefficient computation. One block, 512 threads (8 rows x 64 cols).
__global__ __launch_bounds__(512) void schema_kernel(
    const float* __restrict__ schema_x, const int* __restrict__ sei,
    const float* __restrict__ preW, const float* __restrict__ preb,
    const float* __restrict__ gcnW, const float* __restrict__ gcnb,
    const float* __restrict__ coW, const float* __restrict__ cob,
    float* __restrict__ out_sf, float* __restrict__ out_ori,
    float* __restrict__ coeffs)
{
    __shared__ float h[SS][HDIM];
    __shared__ float xw[SS][HDIM];
    __shared__ float sf[SS][HDIM];
    __shared__ float deg[SS];
    __shared__ float nrm[32];
    __shared__ int es[32], ed[32];

    int t = threadIdx.x;
    int i = t >> 6, j = t & 63;

    float acc = preb[j];
    for (int k = 0; k < INDIM; k++) acc += schema_x[i * INDIM + k] * preW[j * INDIM + k];
    h[i][j] = acc;
    out_ori[i * HDIM + j] = acc;
    if (t < SS) deg[t] = 0.0f;
    __syncthreads();

    if (t < 32) {
        int s, d;
        if (t < 24) { s = sei[t]; d = sei[24 + t]; }
        else        { s = t - 24; d = t - 24; }
        es[t] = s; ed[t] = d;
        atomicAdd(&deg[d], 1.0f);
    }
    __syncthreads();
    if (t < 32) {
        nrm[t] = rsqrtf(fmaxf(deg[es[t]], 1e-12f)) * rsqrtf(fmaxf(deg[ed[t]], 1e-12f));
    }
    float a2 = 0.0f;
    for (int k = 0; k < HDIM; k++) a2 += h[i][k] * gcnW[j * HDIM + k];
    xw[i][j] = a2;
    __syncthreads();

    float o = gcnb[j];
    for (int e = 0; e < 32; e++) {
        if (ed[e] == i) o += xw[es[e]][j] * nrm[e];
    }
    float s = fmaxf(o, 0.0f);
    sf[i][j] = s;
    out_sf[i * HDIM + j] = s;
    __syncthreads();

    if (t < 24) {
        int ty = t >> 3, ii = t & 7;
        int srow = (ty == 1) ? 1 : 0;
        int drow = (ty == 0) ? 1 : 0;
        float a = cob[ii];
        for (int k = 0; k < HDIM; k++) a += sf[srow][k] * coW[ii * (2 * HDIM) + k];
        for (int k = 0; k < HDIM; k++) a += sf[drow][k] * coW[ii * (2 * HDIM) + HDIM + k];
        coeffs[ty * 8 + ii] = a;
    }
}

__global__ __launch_bounds__(256) void build_w_kernel(
    const float* __restrict__ bases, const float* __restrict__ coeffs,
    float* __restrict__ W)
{
    int idx = blockIdx.x * blockDim.x + threadIdx.x;
    int lt = idx >> 14;
    int jk = idx & 16383;
    int l = lt / 3, ty = lt % 3;
    float acc = 0.0f;
#pragma unroll
    for (int i = 0; i < NBASES; i++)
        acc += coeffs[ty * 8 + i] * bases[((size_t)(l * NBASES + i) << 14) + jk];
    W[idx] = acc;
}

// ---------------- CSR build (once per launch; edges are layer-invariant) ----

__global__ __launch_bounds__(256) void hist_kernel(
    const int* __restrict__ ab, const int* __restrict__ ba,
    const int* __restrict__ aa, int* __restrict__ hist)
{
    int e = blockIdx.x * 256 + threadIdx.x;
    int ty = blockIdx.y;
    if (e >= EDGES) return;
    const int* ei = (ty == 0) ? ab : (ty == 1) ? ba : aa;
    atomicAdd(&hist[ty * NN + ei[EDGES + e]], 1);
}

// One block of 1024 per edge type: exclusive scan of hist -> rowptr, pos.
__global__ __launch_bounds__(1024) void scan_kernel(
    const int* __restrict__ hist, int* __restrict__ rowptr, int* __restrict__ pos)
{
    const int CH = 49;  // 1024*49 = 50176 >= 50000
    int ty = blockIdx.x;
    const int* h = hist + ty * NN;
    int* rp = rowptr + ty * (NN + 1);
    int* ps = pos + ty * NN;

    __shared__ int sbuf[1024];
    int t = threadIdx.x;
    int start = t * CH;
    int end = min(start + CH, NN);

    int sum = 0;
    for (int i = start; i < end; i++) sum += h[i];
    sbuf[t] = sum;
    __syncthreads();
    for (int off = 1; off < 1024; off <<= 1) {
        int v = (t >= off) ? sbuf[t - off] : 0;
        __syncthreads();
        sbuf[t] += v;
        __syncthreads();
    }
    int run = sbuf[t] - sum;   // exclusive prefix
    for (int i = start; i < end; i++) {
        rp[i] = run; ps[i] = run;
        run += h[i];
    }
    if (t == 1023) rp[NN] = run;   // == EDGES
}

__global__ __launch_bounds__(256) void fill_kernel(
    const int* __restrict__ ab, const int* __restrict__ ba,
    const int* __restrict__ aa, int* __restrict__ pos, int* __restrict__ col)
{
    int e = blockIdx.x * 256 + threadIdx.x;
    int ty = blockIdx.y;
    if (e >= EDGES) return;
    const int* ei = (ty == 0) ? ab : (ty == 1) ? ba : aa;
    int src = ei[e], dst = ei[EDGES + e];
    int slot = atomicAdd(&pos[ty * NN + dst], 1);
    col[(size_t)ty * EDGES + slot] = src;
}

// ---------------- fused gather + (mean + x)@W^T + bias -> LN -> ReLU --------

// Software-pipelined gather: 8 value loads in flight while the NEXT batch of
// neighbor indices is fetched. Tail handled by clamping (min(idx,e-1)) +
// masked accumulate — no CSR padding needed. s/e are block-uniform so all
// branches here are wave-uniform.
__device__ __forceinline__ float gather_row(
    const float* __restrict__ xsrc, const int* __restrict__ col,
    int s, int e, int t)
{
    if (s >= e) return 0.0f;
    float g = 0.0f;
    int i = s;
    int cs[8];
#pragma unroll
    for (int j = 0; j < 8; j++) cs[j] = col[min(i + j, e - 1)];
    for (;;) {
        float v[8];
#pragma unroll
        for (int j = 0; j < 8; j++) v[j] = xsrc[(size_t)cs[j] * CDIM + t];
        int inext = i + 8;
        bool more = inext < e;
        if (more) {
#pragma unroll
            for (int j = 0; j < 8; j++) cs[j] = col[min(inext + j, e - 1)];
        }
#pragma unroll
        for (int j = 0; j < 8; j++) g += (i + j < e) ? v[j] : 0.0f;
        if (!more) break;
        i = inext;
    }
    return g;
}

// b-side: mean(x_a[in-edges]) + x_b, @W^T + bias -> LN -> ReLU
__global__ __launch_bounds__(128) void fuse_b_kernel(
    const float* __restrict__ xsrc, const float* __restrict__ xdst,
    const int* __restrict__ rowptr, const int* __restrict__ col,
    const float* __restrict__ W, const float* __restrict__ bias,
    const float* __restrict__ lnw, const float* __restrict__ lnb,
    float* __restrict__ xnext)
{
    const int R = 8;
    __shared__ __align__(16) float U[R][CDIM];
    __shared__ float red[2][2];
    int t = threadIdx.x;
    int base = blockIdx.x * R;

    for (int r = 0; r < R; r++) {
        int row = base + r;
        int s = rowptr[row], e = rowptr[row + 1];
        float g = gather_row(xsrc, col, s, e, t);
        float inv = 1.0f / (float)max(e - s, 1);
        U[r][t] = g * inv + xdst[(size_t)row * CDIM + t];
    }
    __syncthreads();

    float acc[R];
    float b = bias[t];
#pragma unroll
    for (int r = 0; r < R; r++) acc[r] = b;

    const float4* Wr = (const float4*)(W + (size_t)t * CDIM);
    for (int k4 = 0; k4 < 32; k4++) {
        float4 w = Wr[k4];
#pragma unroll
        for (int r = 0; r < R; r++) {
            float4 u = *(const float4*)&U[r][k4 * 4];
            acc[r] += u.x * w.x + u.y * w.y + u.z * w.z + u.w * w.w;
        }
    }

    float lw = lnw[t], lb = lnb[t];
    int wid = t >> 6, lane = t & 63;
    for (int r = 0; r < R; r++) {
        float v = acc[r];
        float s = v, s2 = v * v;
        for (int off = 32; off > 0; off >>= 1) {
            s += __shfl_down(s, off, 64);
            s2 += __shfl_down(s2, off, 64);
        }
        if (lane == 0) { red[wid][0] = s; red[wid][1] = s2; }
        __syncthreads();
        float tot = red[0][0] + red[1][0];
        float tot2 = red[0][1] + red[1][1];
        float mu = tot * (1.0f / CDIM);
        float var = tot2 * (1.0f / CDIM) - mu * mu;
        float rs = rsqrtf(var + 1e-5f);
        float o = (v - mu) * rs * lw + lb;
        xnext[(size_t)(base + r) * CDIM + t] = fmaxf(o, 0.0f);
        __syncthreads();
    }
}

// a-side: (mean_ba(x_b)+x_a)@W1^T + (mean_aa(x_a)+x_a)@W2^T + b1+b2 -> LN -> ReLU
__global__ __launch_bounds__(128) void fuse_a_kernel(
    const float* __restrict__ xsrc1, const int* __restrict__ rowptr1, const int* __restrict__ col1,
    const float* __restrict__ xsrc2, const int* __restrict__ rowptr2, const int* __restrict__ col2,
    const float* __restrict__ xdst,
    const float* __restrict__ W1, const float* __restrict__ W2,
    const float* __restrict__ bias1, const float* __restrict__ bias2,
    const float* __restrict__ lnw, const float* __restrict__ lnb,
    float* __restrict__ xnext)
{
    const int R = 8;
    __shared__ __align__(16) float U[R][CDIM];
    __shared__ __align__(16) float V[R][CDIM];
    __shared__ float red[2][2];
    int t = threadIdx.x;
    int base = blockIdx.x * R;

    for (int r = 0; r < R; r++) {
        int row = base + r;
        float xv = xdst[(size_t)row * CDIM + t];
        int s1 = rowptr1[row], e1 = rowptr1[row + 1];
        float g1 = gather_row(xsrc1, col1, s1, e1, t);
        U[r][t] = g1 * (1.0f / (float)max(e1 - s1, 1)) + xv;
        int s2 = rowptr2[row], e2 = rowptr2[row + 1];
        float g2 = gather_row(xsrc2, col2, s2, e2, t);
        V[r][t] = g2 * (1.0f / (float)max(e2 - s2, 1)) + xv;
    }
    __syncthreads();

    float acc[R];
    float b = bias1[t] + bias2[t];
#pragma unroll
    for (int r = 0; r < R; r++) acc[r] = b;

    const float4* W1r = (const float4*)(W1 + (size_t)t * CDIM);
    const float4* W2r = (const float4*)(W2 + (size_t)t * CDIM);
    for (int k4 = 0; k4 < 32; k4++) {
        float4 w1 = W1r[k4];
        float4 w2 = W2r[k4];
#pragma unroll
        for (int r = 0; r < R; r++) {
            float4 u = *(const float4*)&U[r][k4 * 4];
            float4 v = *(const float4*)&V[r][k4 * 4];
            acc[r] += u.x * w1.x + u.y * w1.y + u.z * w1.z + u.w * w1.w
                    + v.x * w2.x + v.y * w2.y + v.z * w2.z + v.w * w2.w;
        }
    }

    float lw = lnw[t], lb = lnb[t];
    int wid = t >> 6, lane = t & 63;
    for (int r = 0; r < R; r++) {
        float v = acc[r];
        float s = v, s2 = v * v;
        for (int off = 32; off > 0; off >>= 1) {
            s += __shfl_down(s, off, 64);
            s2 += __shfl_down(s2, off, 64);
        }
        if (lane == 0) { red[wid][0] = s; red[wid][1] = s2; }
        __syncthreads();
        float tot = red[0][0] + red[1][0];
        float tot2 = red[0][1] + red[1][1];
        float mu = tot * (1.0f / CDIM);
        float var = tot2 * (1.0f / CDIM) - mu * mu;
        float rs = rsqrtf(var + 1e-5f);
        float o = (v - mu) * rs * lw + lb;
        xnext[(size_t)(base + r) * CDIM + t] = fmaxf(o, 0.0f);
        __syncthreads();
    }
}

extern "C" void kernel_launch(void* const* d_in, const int* in_sizes, int n_in,
                              void* d_out, int out_size, void* d_ws, size_t ws_size,
                              hipStream_t stream)
{
    const float* x_a      = (const float*)d_in[0];
    const float* x_b      = (const float*)d_in[1];
    const float* schema_x = (const float*)d_in[2];
    const int*   e_ab     = (const int*)d_in[3];
    const int*   e_ba     = (const int*)d_in[4];
    const int*   e_aa     = (const int*)d_in[5];
    const int*   sei      = (const int*)d_in[6];
    const float* preW     = (const float*)d_in[7];
    const float* preb     = (const float*)d_in[8];
    const float* gcnW     = (const float*)d_in[9];
    const float* gcnb     = (const float*)d_in[10];
    const float* coW      = (const float*)d_in[11];
    const float* cob      = (const float*)d_in[12];
    const float* bases    = (const float*)d_in[13];
    const float* sbias    = (const float*)d_in[14];
    const float* lnw      = (const float*)d_in[15];
    const float* lnb      = (const float*)d_in[16];

    float* out     = (float*)d_out;
    float* out_xa  = out;
    float* out_xb  = out + 6400000;
    float* out_sf  = out + 12800000;
    float* out_ori = out + 12800512;

    float* ws = (float*)d_ws;
    int*   col    = (int*)ws;                 // [3*E]
    int*   rowptr = (int*)(ws + 2400000);     // [3*(NN+1)]
    int*   pos    = (int*)(ws + 2550003);     // [3*NN]
    int*   hist   = (int*)(ws + 2700003);     // [3*NN]
    float* xa_buf = ws + 2850016;
    float* xb_buf = ws + 9250016;
    float* Wbuf   = ws + 15650016;
    float* coeffs = ws + 15748320;

    // schema + dynamic weights
    schema_kernel<<<1, 512, 0, stream>>>(schema_x, sei, preW, preb, gcnW, gcnb,
                                         coW, cob, out_sf, out_ori, coeffs);
    build_w_kernel<<<384, 256, 0, stream>>>(bases, coeffs, Wbuf);

    // CSR build (layer-invariant)
    hipMemsetAsync(hist, 0, 3 * NN * sizeof(int), stream);
    dim3 egrid(EDGES / 256, 3);
    hist_kernel<<<egrid, 256, 0, stream>>>(e_ab, e_ba, e_aa, hist);
    scan_kernel<<<3, 1024, 0, stream>>>(hist, rowptr, pos);
    fill_kernel<<<egrid, 256, 0, stream>>>(e_ab, e_ba, e_aa, pos, col);

    const int* rp_ab = rowptr;
    const int* rp_ba = rowptr + (NN + 1);
    const int* rp_aa = rowptr + 2 * (NN + 1);
    const int* col_ab = col;
    const int* col_ba = col + EDGES;
    const int* col_aa = col + 2 * EDGES;

    for (int l = 0; l < 2; l++) {
        const float* xa_cur = (l == 0) ? x_a : xa_buf;
        const float* xb_cur = (l == 0) ? x_b : xb_buf;
        const float* Wab = Wbuf + (size_t)(l * 3 + 0) * 16384;
        const float* Wba = Wbuf + (size_t)(l * 3 + 1) * 16384;
        const float* Waa = Wbuf + (size_t)(l * 3 + 2) * 16384;
        float* xa_nxt = (l == 0) ? xa_buf : out_xa;
        float* xb_nxt = (l == 0) ? xb_buf : out_xb;

        fuse_b_kernel<<<NB / 8, 128, 0, stream>>>(
            xa_cur, xb_cur, rp_ab, col_ab, Wab,
            sbias + (size_t)(l * 3 + 0) * 128,
            lnw + (size_t)(l * 2 + 1) * 128, lnb + (size_t)(l * 2 + 1) * 128,
            xb_nxt);
        fuse_a_kernel<<<NA / 8, 128, 0, stream>>>(
            xb_cur, rp_ba, col_ba, xa_cur, rp_aa, col_aa, xa_cur,
            Wba, Waa,
            sbias + (size_t)(l * 3 + 1) * 128, sbias + (size_t)(l * 3 + 2) * 128,
            lnw + (size_t)(l * 2 + 0) * 128, lnb + (size_t)(l * 2 + 0) * 128,
            xa_nxt);
    }
}

// Round 4
// 1234.414 us; speedup vs baseline: 2.1213x; 1.0219x over previous
//
#include <hip/hip_runtime.h>

#define NA 50000
#define NB 50000
#define NN 50000
#define CDIM 128
#define EDGES 800000
#define SS 8
#define INDIM 64
#define HDIM 64
#define NBASES 8

// ---------------------------------------------------------------------------
// Workspace layout (4-byte element offsets):
//   0         col      [3*E]      int
//   2400000   rowptr   [3*(NN+1)] int
//   2550003   pos      [3*NN]     int
//   2700003   hist     [3*NN]     int
//   2850016   xa_buf   [NA*128]   float  (layer-0 output a, fp32)
//   9250016   xb_buf   [NB*128]   float
//   15650016  W        [6*128*128] float
//   15748320  coeffs   [3*8]      float
//   15748352  xa_bf0   ushort[NA*128]  (bf16 of x_a)       = 3.2M floats
//   18948352  xb_bf0   ushort[NB*128]
//   22148352  xa_bf1   ushort[NA*128]  (bf16 of layer-0 a)
//   25348352  xb_bf1   ushort[NB*128]
//   28548352  end  (~114 MB)
// ---------------------------------------------------------------------------

__device__ __forceinline__ float bf2f(unsigned short b) {
    return __uint_as_float(((unsigned)b) << 16);
}
__device__ __forceinline__ unsigned short f2bf(float f) {
    unsigned u = __float_as_uint(f);
    return (unsigned short)((u + 0x7FFFu + ((u >> 16) & 1u)) >> 16);
}

// Schema GCN + coefficient computation. One block, 512 threads (8 rows x 64 cols).
__global__ __launch_bounds__(512) void schema_kernel(
    const float* __restrict__ schema_x, const int* __restrict__ sei,
    const float* __restrict__ preW, const float* __restrict__ preb,
    const float* __restrict__ gcnW, const float* __restrict__ gcnb,
    const float* __restrict__ coW, const float* __restrict__ cob,
    float* __restrict__ out_sf, float* __restrict__ out_ori,
    float* __restrict__ coeffs)
{
    __shared__ float h[SS][HDIM];
    __shared__ float xw[SS][HDIM];
    __shared__ float sf[SS][HDIM];
    __shared__ float deg[SS];
    __shared__ float nrm[32];
    __shared__ int es[32], ed[32];

    int t = threadIdx.x;
    int i = t >> 6, j = t & 63;

    float acc = preb[j];
    for (int k = 0; k < INDIM; k++) acc += schema_x[i * INDIM + k] * preW[j * INDIM + k];
    h[i][j] = acc;
    out_ori[i * HDIM + j] = acc;
    if (t < SS) deg[t] = 0.0f;
    __syncthreads();

    if (t < 32) {
        int s, d;
        if (t < 24) { s = sei[t]; d = sei[24 + t]; }
        else        { s = t - 24; d = t - 24; }
        es[t] = s; ed[t] = d;
        atomicAdd(&deg[d], 1.0f);
    }
    __syncthreads();
    if (t < 32) {
        nrm[t] = rsqrtf(fmaxf(deg[es[t]], 1e-12f)) * rsqrtf(fmaxf(deg[ed[t]], 1e-12f));
    }
    float a2 = 0.0f;
    for (int k = 0; k < HDIM; k++) a2 += h[i][k] * gcnW[j * HDIM + k];
    xw[i][j] = a2;
    __syncthreads();

    float o = gcnb[j];
    for (int e = 0; e < 32; e++) {
        if (ed[e] == i) o += xw[es[e]][j] * nrm[e];
    }
    float s = fmaxf(o, 0.0f);
    sf[i][j] = s;
    out_sf[i * HDIM + j] = s;
    __syncthreads();

    if (t < 24) {
        int ty = t >> 3, ii = t & 7;
        int srow = (ty == 1) ? 1 : 0;
        int drow = (ty == 0) ? 1 : 0;
        float a = cob[ii];
        for (int k = 0; k < HDIM; k++) a += sf[srow][k] * coW[ii * (2 * HDIM) + k];
        for (int k = 0; k < HDIM; k++) a += sf[drow][k] * coW[ii * (2 * HDIM) + HDIM + k];
        coeffs[ty * 8 + ii] = a;
    }
}

__global__ __launch_bounds__(256) void build_w_kernel(
    const float* __restrict__ bases, const float* __restrict__ coeffs,
    float* __restrict__ W)
{
    int idx = blockIdx.x * blockDim.x + threadIdx.x;
    int lt = idx >> 14;
    int jk = idx & 16383;
    int l = lt / 3, ty = lt % 3;
    float acc = 0.0f;
#pragma unroll
    for (int i = 0; i < NBASES; i++)
        acc += coeffs[ty * 8 + i] * bases[((size_t)(l * NBASES + i) << 14) + jk];
    W[idx] = acc;
}

// fp32 -> bf16 table conversion (n divisible by 4)
__global__ __launch_bounds__(256) void tobf16_kernel(
    const float* __restrict__ in, unsigned short* __restrict__ out, int n)
{
    int i = (blockIdx.x * 256 + threadIdx.x) * 4;
    if (i >= n) return;
    float4 f = *(const float4*)(in + i);
    ushort4 o;
    o.x = f2bf(f.x); o.y = f2bf(f.y); o.z = f2bf(f.z); o.w = f2bf(f.w);
    *(ushort4*)(out + i) = o;
}

// ---------------- CSR build (once per launch; edges are layer-invariant) ----

__global__ __launch_bounds__(256) void hist_kernel(
    const int* __restrict__ ab, const int* __restrict__ ba,
    const int* __restrict__ aa, int* __restrict__ hist)
{
    int e = blockIdx.x * 256 + threadIdx.x;
    int ty = blockIdx.y;
    if (e >= EDGES) return;
    const int* ei = (ty == 0) ? ab : (ty == 1) ? ba : aa;
    atomicAdd(&hist[ty * NN + ei[EDGES + e]], 1);
}

__global__ __launch_bounds__(1024) void scan_kernel(
    const int* __restrict__ hist, int* __restrict__ rowptr, int* __restrict__ pos)
{
    const int CH = 49;
    int ty = blockIdx.x;
    const int* h = hist + ty * NN;
    int* rp = rowptr + ty * (NN + 1);
    int* ps = pos + ty * NN;

    __shared__ int sbuf[1024];
    int t = threadIdx.x;
    int start = t * CH;
    int end = min(start + CH, NN);

    int sum = 0;
    for (int i = start; i < end; i++) sum += h[i];
    sbuf[t] = sum;
    __syncthreads();
    for (int off = 1; off < 1024; off <<= 1) {
        int v = (t >= off) ? sbuf[t - off] : 0;
        __syncthreads();
        sbuf[t] += v;
        __syncthreads();
    }
    int run = sbuf[t] - sum;
    for (int i = start; i < end; i++) {
        rp[i] = run; ps[i] = run;
        run += h[i];
    }
    if (t == 1023) rp[NN] = run;
}

__global__ __launch_bounds__(256) void fill_kernel(
    const int* __restrict__ ab, const int* __restrict__ ba,
    const int* __restrict__ aa, int* __restrict__ pos, int* __restrict__ col)
{
    int e = blockIdx.x * 256 + threadIdx.x;
    int ty = blockIdx.y;
    if (e >= EDGES) return;
    const int* ei = (ty == 0) ? ab : (ty == 1) ? ba : aa;
    int src = ei[e], dst = ei[EDGES + e];
    int slot = atomicAdd(&pos[ty * NN + dst], 1);
    col[(size_t)ty * EDGES + slot] = src;
}

// ---------------- fused gather + (mean + x)@W^T + bias -> LN -> ReLU --------

// bf16 gather, 16-deep software pipeline. Tail via clamp + masked accumulate.
// s/e are block-uniform -> wave-uniform branches.
__device__ __forceinline__ float gather_row_bf(
    const unsigned short* __restrict__ xsrc, const int* __restrict__ col,
    int s, int e, int t)
{
    if (s >= e) return 0.0f;
    float g = 0.0f;
    int i = s;
    int cs[16];
#pragma unroll
    for (int j = 0; j < 16; j++) cs[j] = col[min(i + j, e - 1)];
    for (;;) {
        unsigned short v[16];
#pragma unroll
        for (int j = 0; j < 16; j++) v[j] = xsrc[(size_t)cs[j] * CDIM + t];
        int inext = i + 16;
        bool more = inext < e;
        if (more) {
#pragma unroll
            for (int j = 0; j < 16; j++) cs[j] = col[min(inext + j, e - 1)];
        }
#pragma unroll
        for (int j = 0; j < 16; j++) g += (i + j < e) ? bf2f(v[j]) : 0.0f;
        if (!more) break;
        i = inext;
    }
    return g;
}

// b-side: mean(bf16 x_a[in-edges]) + x_b, @W^T + bias -> LN -> ReLU
__global__ __launch_bounds__(128) void fuse_b_kernel(
    const unsigned short* __restrict__ xsrc, const float* __restrict__ xdst,
    const int* __restrict__ rowptr, const int* __restrict__ col,
    const float* __restrict__ W, const float* __restrict__ bias,
    const float* __restrict__ lnw, const float* __restrict__ lnb,
    float* __restrict__ xnext, unsigned short* __restrict__ xnext_bf)
{
    const int R = 8;
    __shared__ __align__(16) float U[R][CDIM];
    __shared__ float red[2][2];
    int t = threadIdx.x;
    int base = blockIdx.x * R;

    for (int r = 0; r < R; r++) {
        int row = base + r;
        int s = rowptr[row], e = rowptr[row + 1];
        float g = gather_row_bf(xsrc, col, s, e, t);
        float inv = 1.0f / (float)max(e - s, 1);
        U[r][t] = g * inv + xdst[(size_t)row * CDIM + t];
    }
    __syncthreads();

    float acc[R];
    float b = bias[t];
#pragma unroll
    for (int r = 0; r < R; r++) acc[r] = b;

    const float4* Wr = (const float4*)(W + (size_t)t * CDIM);
    for (int k4 = 0; k4 < 32; k4++) {
        float4 w = Wr[k4];
#pragma unroll
        for (int r = 0; r < R; r++) {
            float4 u = *(const float4*)&U[r][k4 * 4];
            acc[r] += u.x * w.x + u.y * w.y + u.z * w.z + u.w * w.w;
        }
    }

    float lw = lnw[t], lb = lnb[t];
    int wid = t >> 6, lane = t & 63;
    for (int r = 0; r < R; r++) {
        float v = acc[r];
        float s = v, s2 = v * v;
        for (int off = 32; off > 0; off >>= 1) {
            s += __shfl_down(s, off, 64);
            s2 += __shfl_down(s2, off, 64);
        }
        if (lane == 0) { red[wid][0] = s; red[wid][1] = s2; }
        __syncthreads();
        float tot = red[0][0] + red[1][0];
        float tot2 = red[0][1] + red[1][1];
        float mu = tot * (1.0f / CDIM);
        float var = tot2 * (1.0f / CDIM) - mu * mu;
        float rs = rsqrtf(var + 1e-5f);
        float o = (v - mu) * rs * lw + lb;
        float rl = fmaxf(o, 0.0f);
        size_t oi = (size_t)(base + r) * CDIM + t;
        xnext[oi] = rl;
        if (xnext_bf) xnext_bf[oi] = f2bf(rl);
        __syncthreads();
    }
}

// a-side: (mean_ba(bf x_b)+x_a)@W1^T + (mean_aa(bf x_a)+x_a)@W2^T + b1+b2 -> LN -> ReLU
__global__ __launch_bounds__(128) void fuse_a_kernel(
    const unsigned short* __restrict__ xsrc1, const int* __restrict__ rowptr1, const int* __restrict__ col1,
    const unsigned short* __restrict__ xsrc2, const int* __restrict__ rowptr2, const int* __restrict__ col2,
    const float* __restrict__ xdst,
    const float* __restrict__ W1, const float* __restrict__ W2,
    const float* __restrict__ bias1, const float* __restrict__ bias2,
    const float* __restrict__ lnw, const float* __restrict__ lnb,
    float* __restrict__ xnext, unsigned short* __restrict__ xnext_bf)
{
    const int R = 8;
    __shared__ __align__(16) float U[R][CDIM];
    __shared__ __align__(16) float V[R][CDIM];
    __shared__ float red[2][2];
    int t = threadIdx.x;
    int base = blockIdx.x * R;

    for (int r = 0; r < R; r++) {
        int row = base + r;
        float xv = xdst[(size_t)row * CDIM + t];
        int s1 = rowptr1[row], e1 = rowptr1[row + 1];
        float g1 = gather_row_bf(xsrc1, col1, s1, e1, t);
        U[r][t] = g1 * (1.0f / (float)max(e1 - s1, 1)) + xv;
        int s2 = rowptr2[row], e2 = rowptr2[row + 1];
        float g2 = gather_row_bf(xsrc2, col2, s2, e2, t);
        V[r][t] = g2 * (1.0f / (float)max(e2 - s2, 1)) + xv;
    }
    __syncthreads();

    float acc[R];
    float b = bias1[t] + bias2[t];
#pragma unroll
    for (int r = 0; r < R; r++) acc[r] = b;

    const float4* W1r = (const float4*)(W1 + (size_t)t * CDIM);
    const float4* W2r = (const float4*)(W2 + (size_t)t * CDIM);
    for (int k4 = 0; k4 < 32; k4++) {
        float4 w1 = W1r[k4];
        float4 w2 = W2r[k4];
#pragma unroll
        for (int r = 0; r < R; r++) {
            float4 u = *(const float4*)&U[r][k4 * 4];
            float4 v = *(const float4*)&V[r][k4 * 4];
            acc[r] += u.x * w1.x + u.y * w1.y + u.z * w1.z + u.w * w1.w
                    + v.x * w2.x + v.y * w2.y + v.z * w2.z + v.w * w2.w;
        }
    }

    float lw = lnw[t], lb = lnb[t];
    int wid = t >> 6, lane = t & 63;
    for (int r = 0; r < R; r++) {
        float v = acc[r];
        float s = v, s2 = v * v;
        for (int off = 32; off > 0; off >>= 1) {
            s += __shfl_down(s, off, 64);
            s2 += __shfl_down(s2, off, 64);
        }
        if (lane == 0) { red[wid][0] = s; red[wid][1] = s2; }
        __syncthreads();
        float tot = red[0][0] + red[1][0];
        float tot2 = red[0][1] + red[1][1];
        float mu = tot * (1.0f / CDIM);
        float var = tot2 * (1.0f / CDIM) - mu * mu;
        float rs = rsqrtf(var + 1e-5f);
        float o = (v - mu) * rs * lw + lb;
        float rl = fmaxf(o, 0.0f);
        size_t oi = (size_t)(base + r) * CDIM + t;
        xnext[oi] = rl;
        if (xnext_bf) xnext_bf[oi] = f2bf(rl);
        __syncthreads();
    }
}

extern "C" void kernel_launch(void* const* d_in, const int* in_sizes, int n_in,
                              void* d_out, int out_size, void* d_ws, size_t ws_size,
                              hipStream_t stream)
{
    const float* x_a      = (const float*)d_in[0];
    const float* x_b      = (const float*)d_in[1];
    const float* schema_x = (const float*)d_in[2];
    const int*   e_ab     = (const int*)d_in[3];
    const int*   e_ba     = (const int*)d_in[4];
    const int*   e_aa     = (const int*)d_in[5];
    const int*   sei      = (const int*)d_in[6];
    const float* preW     = (const float*)d_in[7];
    const float* preb     = (const float*)d_in[8];
    const float* gcnW     = (const float*)d_in[9];
    const float* gcnb     = (const float*)d_in[10];
    const float* coW      = (const float*)d_in[11];
    const float* cob      = (const float*)d_in[12];
    const float* bases    = (const float*)d_in[13];
    const float* sbias    = (const float*)d_in[14];
    const float* lnw      = (const float*)d_in[15];
    const float* lnb      = (const float*)d_in[16];

    float* out     = (float*)d_out;
    float* out_xa  = out;
    float* out_xb  = out + 6400000;
    float* out_sf  = out + 12800000;
    float* out_ori = out + 12800512;

    float* ws = (float*)d_ws;
    int*   col    = (int*)ws;
    int*   rowptr = (int*)(ws + 2400000);
    int*   pos    = (int*)(ws + 2550003);
    int*   hist   = (int*)(ws + 2700003);
    float* xa_buf = ws + 2850016;
    float* xb_buf = ws + 9250016;
    float* Wbuf   = ws + 15650016;
    float* coeffs = ws + 15748320;
    unsigned short* xa_bf0 = (unsigned short*)(ws + 15748352);
    unsigned short* xb_bf0 = (unsigned short*)(ws + 18948352);
    unsigned short* xa_bf1 = (unsigned short*)(ws + 22148352);
    unsigned short* xb_bf1 = (unsigned short*)(ws + 25348352);

    // schema + dynamic weights
    schema_kernel<<<1, 512, 0, stream>>>(schema_x, sei, preW, preb, gcnW, gcnb,
                                         coW, cob, out_sf, out_ori, coeffs);
    build_w_kernel<<<384, 256, 0, stream>>>(bases, coeffs, Wbuf);

    // bf16 copies of the input node tables
    tobf16_kernel<<<(NA * CDIM / 4 + 255) / 256, 256, 0, stream>>>(x_a, xa_bf0, NA * CDIM);
    tobf16_kernel<<<(NB * CDIM / 4 + 255) / 256, 256, 0, stream>>>(x_b, xb_bf0, NB * CDIM);

    // CSR build (layer-invariant)
    hipMemsetAsync(hist, 0, 3 * NN * sizeof(int), stream);
    dim3 egrid(EDGES / 256, 3);
    hist_kernel<<<egrid, 256, 0, stream>>>(e_ab, e_ba, e_aa, hist);
    scan_kernel<<<3, 1024, 0, stream>>>(hist, rowptr, pos);
    fill_kernel<<<egrid, 256, 0, stream>>>(e_ab, e_ba, e_aa, pos, col);

    const int* rp_ab = rowptr;
    const int* rp_ba = rowptr + (NN + 1);
    const int* rp_aa = rowptr + 2 * (NN + 1);
    const int* col_ab = col;
    const int* col_ba = col + EDGES;
    const int* col_aa = col + 2 * EDGES;

    for (int l = 0; l < 2; l++) {
        const float* xa_cur = (l == 0) ? x_a : xa_buf;
        const float* xb_cur = (l == 0) ? x_b : xb_buf;
        const unsigned short* xa_bf = (l == 0) ? xa_bf0 : xa_bf1;
        const unsigned short* xb_bf = (l == 0) ? xb_bf0 : xb_bf1;
        const float* Wab = Wbuf + (size_t)(l * 3 + 0) * 16384;
        const float* Wba = Wbuf + (size_t)(l * 3 + 1) * 16384;
        const float* Waa = Wbuf + (size_t)(l * 3 + 2) * 16384;
        float* xa_nxt = (l == 0) ? xa_buf : out_xa;
        float* xb_nxt = (l == 0) ? xb_buf : out_xb;
        unsigned short* xa_nbf = (l == 0) ? xa_bf1 : nullptr;
        unsigned short* xb_nbf = (l == 0) ? xb_bf1 : nullptr;

        fuse_b_kernel<<<NB / 8, 128, 0, stream>>>(
            xa_bf, xb_cur, rp_ab, col_ab, Wab,
            sbias + (size_t)(l * 3 + 0) * 128,
            lnw + (size_t)(l * 2 + 1) * 128, lnb + (size_t)(l * 2 + 1) * 128,
            xb_nxt, xb_nbf);
        fuse_a_kernel<<<NA / 8, 128, 0, stream>>>(
            xb_bf, rp_ba, col_ba, xa_bf, rp_aa, col_aa, xa_cur,
            Wba, Waa,
            sbias + (size_t)(l * 3 + 1) * 128, sbias + (size_t)(l * 3 + 2) * 128,
            lnw + (size_t)(l * 2 + 0) * 128, lnb + (size_t)(l * 2 + 0) * 128,
            xa_nxt, xa_nbf);
    }
}

// Round 5
// 1122.712 us; speedup vs baseline: 2.3324x; 1.0995x over previous
//
#include <hip/hip_runtime.h>

#define NA 50000
#define NB 50000
#define NN 50000
#define CDIM 128
#define EDGES 800000
#define SS 8
#define INDIM 64
#define HDIM 64
#define NBASES 8

// ---------------------------------------------------------------------------
// Workspace layout (4-byte element offsets):
//   0         col      [3*E]      int
//   2400000   rowptr   [3*(NN+1)] int
//   2550003   pos      [3*NN]     int
//   2700003   hist     [3*NN]     int
//   2850016   xa_buf   [NA*128]   float  (layer-0 output a, fp32)
//   9250016   xb_buf   [NB*128]   float
//   15650016  W        [6*128*128] float
//   15748320  coeffs   [3*8]      float
//   15748352  xa_bf0   ushort[NA*128]
//   18948352  xb_bf0   ushort[NB*128]
//   22148352  xa_bf1   ushort[NA*128]
//   25348352  xb_bf1   ushort[NB*128]
//   28548352  end  (~114 MB)
// ---------------------------------------------------------------------------

__device__ __forceinline__ float bf2f(unsigned short b) {
    return __uint_as_float(((unsigned)b) << 16);
}
__device__ __forceinline__ unsigned short f2bf(float f) {
    unsigned u = __float_as_uint(f);
    return (unsigned short)((u + 0x7FFFu + ((u >> 16) & 1u)) >> 16);
}

// Schema GCN + coefficient computation. One block, 512 threads.
__global__ __launch_bounds__(512) void schema_kernel(
    const float* __restrict__ schema_x, const int* __restrict__ sei,
    const float* __restrict__ preW, const float* __restrict__ preb,
    const float* __restrict__ gcnW, const float* __restrict__ gcnb,
    const float* __restrict__ coW, const float* __restrict__ cob,
    float* __restrict__ out_sf, float* __restrict__ out_ori,
    float* __restrict__ coeffs)
{
    __shared__ float h[SS][HDIM];
    __shared__ float xw[SS][HDIM];
    __shared__ float sf[SS][HDIM];
    __shared__ float deg[SS];
    __shared__ float nrm[32];
    __shared__ int es[32], ed[32];

    int t = threadIdx.x;
    int i = t >> 6, j = t & 63;

    float acc = preb[j];
    for (int k = 0; k < INDIM; k++) acc += schema_x[i * INDIM + k] * preW[j * INDIM + k];
    h[i][j] = acc;
    out_ori[i * HDIM + j] = acc;
    if (t < SS) deg[t] = 0.0f;
    __syncthreads();

    if (t < 32) {
        int s, d;
        if (t < 24) { s = sei[t]; d = sei[24 + t]; }
        else        { s = t - 24; d = t - 24; }
        es[t] = s; ed[t] = d;
        atomicAdd(&deg[d], 1.0f);
    }
    __syncthreads();
    if (t < 32) {
        nrm[t] = rsqrtf(fmaxf(deg[es[t]], 1e-12f)) * rsqrtf(fmaxf(deg[ed[t]], 1e-12f));
    }
    float a2 = 0.0f;
    for (int k = 0; k < HDIM; k++) a2 += h[i][k] * gcnW[j * HDIM + k];
    xw[i][j] = a2;
    __syncthreads();

    float o = gcnb[j];
    for (int e = 0; e < 32; e++) {
        if (ed[e] == i) o += xw[es[e]][j] * nrm[e];
    }
    float s = fmaxf(o, 0.0f);
    sf[i][j] = s;
    out_sf[i * HDIM + j] = s;
    __syncthreads();

    if (t < 24) {
        int ty = t >> 3, ii = t & 7;
        int srow = (ty == 1) ? 1 : 0;
        int drow = (ty == 0) ? 1 : 0;
        float a = cob[ii];
        for (int k = 0; k < HDIM; k++) a += sf[srow][k] * coW[ii * (2 * HDIM) + k];
        for (int k = 0; k < HDIM; k++) a += sf[drow][k] * coW[ii * (2 * HDIM) + HDIM + k];
        coeffs[ty * 8 + ii] = a;
    }
}

__global__ __launch_bounds__(256) void build_w_kernel(
    const float* __restrict__ bases, const float* __restrict__ coeffs,
    float* __restrict__ W)
{
    int idx = blockIdx.x * blockDim.x + threadIdx.x;
    int lt = idx >> 14;
    int jk = idx & 16383;
    int l = lt / 3, ty = lt % 3;
    float acc = 0.0f;
#pragma unroll
    for (int i = 0; i < NBASES; i++)
        acc += coeffs[ty * 8 + i] * bases[((size_t)(l * NBASES + i) << 14) + jk];
    W[idx] = acc;
}

// fp32 -> bf16 table conversion (n divisible by 4)
__global__ __launch_bounds__(256) void tobf16_kernel(
    const float* __restrict__ in, unsigned short* __restrict__ out, int n)
{
    int i = (blockIdx.x * 256 + threadIdx.x) * 4;
    if (i >= n) return;
    float4 f = *(const float4*)(in + i);
    ushort4 o;
    o.x = f2bf(f.x); o.y = f2bf(f.y); o.z = f2bf(f.z); o.w = f2bf(f.w);
    *(ushort4*)(out + i) = o;
}

// ---------------- CSR build (once per launch) -------------------------------

__global__ __launch_bounds__(256) void hist_kernel(
    const int* __restrict__ ab, const int* __restrict__ ba,
    const int* __restrict__ aa, int* __restrict__ hist)
{
    int e = blockIdx.x * 256 + threadIdx.x;
    int ty = blockIdx.y;
    if (e >= EDGES) return;
    const int* ei = (ty == 0) ? ab : (ty == 1) ? ba : aa;
    atomicAdd(&hist[ty * NN + ei[EDGES + e]], 1);
}

__global__ __launch_bounds__(1024) void scan_kernel(
    const int* __restrict__ hist, int* __restrict__ rowptr, int* __restrict__ pos)
{
    const int CH = 49;
    int ty = blockIdx.x;
    const int* h = hist + ty * NN;
    int* rp = rowptr + ty * (NN + 1);
    int* ps = pos + ty * NN;

    __shared__ int sbuf[1024];
    int t = threadIdx.x;
    int start = t * CH;
    int end = min(start + CH, NN);

    int sum = 0;
    for (int i = start; i < end; i++) sum += h[i];
    sbuf[t] = sum;
    __syncthreads();
    for (int off = 1; off < 1024; off <<= 1) {
        int v = (t >= off) ? sbuf[t - off] : 0;
        __syncthreads();
        sbuf[t] += v;
        __syncthreads();
    }
    int run = sbuf[t] - sum;
    for (int i = start; i < end; i++) {
        rp[i] = run; ps[i] = run;
        run += h[i];
    }
    if (t == 1023) rp[NN] = run;
}

__global__ __launch_bounds__(256) void fill_kernel(
    const int* __restrict__ ab, const int* __restrict__ ba,
    const int* __restrict__ aa, int* __restrict__ pos, int* __restrict__ col)
{
    int e = blockIdx.x * 256 + threadIdx.x;
    int ty = blockIdx.y;
    if (e >= EDGES) return;
    const int* ei = (ty == 0) ? ab : (ty == 1) ? ba : aa;
    int src = ei[e], dst = ei[EDGES + e];
    int slot = atomicAdd(&pos[ty * NN + dst], 1);
    col[(size_t)ty * EDGES + slot] = src;
}

// ---------------- fused gather + (mean + x)@W^T + bias -> LN -> ReLU --------

// Wave-wide 2-edges-per-load gather: lane l = 32*half + cl loads uint2 (4 bf16
// channels 4cl..4cl+3) of edge (i + half); halves combined via shfl_xor(32).
// One 512B load instruction covers 2 full rows -> 4x fewer memory instructions
// than the scalar-per-lane version, 4 KB in flight per gather (D=8 pairs).
// s/e are row-uniform -> all branches wave-uniform.
__device__ __forceinline__ float4 gather_pair_bf(
    const unsigned short* __restrict__ xsrc, const int* __restrict__ col,
    int s, int e, int half, int cl)
{
    float4 g = {0.f, 0.f, 0.f, 0.f};
    int n = e - s;
    if (n <= 0) return g;
    const int D = 8;
    int i = s + half;
    int cs[D];
#pragma unroll
    for (int j = 0; j < D; j++) cs[j] = col[min(i + 2 * j, e - 1)];
    int nsteps = (n + 2 * D - 1) / (2 * D);
    int off = cl << 2;   // element offset within row
    for (int st = 0; st < nsteps; st++) {
        uint2 v[D];
#pragma unroll
        for (int j = 0; j < D; j++)
            v[j] = *(const uint2*)(xsrc + (size_t)cs[j] * CDIM + off);
        int inext = i + 2 * D;
        if (st + 1 < nsteps) {
#pragma unroll
            for (int j = 0; j < D; j++) cs[j] = col[min(inext + 2 * j, e - 1)];
        }
#pragma unroll
        for (int j = 0; j < D; j++) {
            if (i + 2 * j < e) {
                g.x += __uint_as_float(v[j].x << 16);
                g.y += __uint_as_float(v[j].x & 0xffff0000u);
                g.z += __uint_as_float(v[j].y << 16);
                g.w += __uint_as_float(v[j].y & 0xffff0000u);
            }
        }
        i = inext;
    }
    g.x += __shfl_xor(g.x, 32, 64);
    g.y += __shfl_xor(g.y, 32, 64);
    g.z += __shfl_xor(g.z, 32, 64);
    g.w += __shfl_xor(g.w, 32, 64);
    return g;
}

// b-side: mean(bf16 x_a[in-edges]) + x_b, @W^T + bias -> LN -> ReLU
__global__ __launch_bounds__(128) void fuse_b_kernel(
    const unsigned short* __restrict__ xsrc, const float* __restrict__ xdst,
    const int* __restrict__ rowptr, const int* __restrict__ col,
    const float* __restrict__ W, const float* __restrict__ bias,
    const float* __restrict__ lnw, const float* __restrict__ lnb,
    float* __restrict__ xnext, unsigned short* __restrict__ xnext_bf)
{
    const int R = 8;
    __shared__ __align__(16) float U[R][CDIM];
    __shared__ float red[2][2];
    int t = threadIdx.x;
    int base = blockIdx.x * R;
    int wv = t >> 6;              // wave id (0/1)
    int lane = t & 63;
    int half = lane >> 5, cl = lane & 31;

    // wave wv gathers rows wv, wv+2, wv+4, wv+6
    for (int rr = 0; rr < R / 2; rr++) {
        int r = rr * 2 + wv;
        int row = base + r;
        int s = rowptr[row], e = rowptr[row + 1];
        float4 g = gather_pair_bf(xsrc, col, s, e, half, cl);
        if (half == 0) {
            float inv = 1.0f / (float)max(e - s, 1);
            float4 xv = *(const float4*)(xdst + (size_t)row * CDIM + (cl << 2));
            float4 u;
            u.x = g.x * inv + xv.x; u.y = g.y * inv + xv.y;
            u.z = g.z * inv + xv.z; u.w = g.w * inv + xv.w;
            *(float4*)&U[r][cl << 2] = u;
        }
    }
    __syncthreads();

    float acc[R];
    float b = bias[t];
#pragma unroll
    for (int r = 0; r < R; r++) acc[r] = b;

    const float4* Wr = (const float4*)(W + (size_t)t * CDIM);
    for (int k4 = 0; k4 < 32; k4++) {
        float4 w = Wr[k4];
#pragma unroll
        for (int r = 0; r < R; r++) {
            float4 u = *(const float4*)&U[r][k4 * 4];
            acc[r] += u.x * w.x + u.y * w.y + u.z * w.z + u.w * w.w;
        }
    }

    float lw = lnw[t], lb = lnb[t];
    for (int r = 0; r < R; r++) {
        float v = acc[r];
        float s = v, s2 = v * v;
        for (int off = 32; off > 0; off >>= 1) {
            s += __shfl_down(s, off, 64);
            s2 += __shfl_down(s2, off, 64);
        }
        if (lane == 0) { red[wv][0] = s; red[wv][1] = s2; }
        __syncthreads();
        float tot = red[0][0] + red[1][0];
        float tot2 = red[0][1] + red[1][1];
        float mu = tot * (1.0f / CDIM);
        float var = tot2 * (1.0f / CDIM) - mu * mu;
        float rs = rsqrtf(var + 1e-5f);
        float o = (v - mu) * rs * lw + lb;
        float rl = fmaxf(o, 0.0f);
        size_t oi = (size_t)(base + r) * CDIM + t;
        xnext[oi] = rl;
        if (xnext_bf) xnext_bf[oi] = f2bf(rl);
        __syncthreads();
    }
}

// a-side: (mean_ba(bf x_b)+x_a)@W1^T + (mean_aa(bf x_a)+x_a)@W2^T + b1+b2 -> LN -> ReLU
__global__ __launch_bounds__(128) void fuse_a_kernel(
    const unsigned short* __restrict__ xsrc1, const int* __restrict__ rowptr1, const int* __restrict__ col1,
    const unsigned short* __restrict__ xsrc2, const int* __restrict__ rowptr2, const int* __restrict__ col2,
    const float* __restrict__ xdst,
    const float* __restrict__ W1, const float* __restrict__ W2,
    const float* __restrict__ bias1, const float* __restrict__ bias2,
    const float* __restrict__ lnw, const float* __restrict__ lnb,
    float* __restrict__ xnext, unsigned short* __restrict__ xnext_bf)
{
    const int R = 8;
    __shared__ __align__(16) float U[R][CDIM];
    __shared__ __align__(16) float V[R][CDIM];
    __shared__ float red[2][2];
    int t = threadIdx.x;
    int base = blockIdx.x * R;
    int wv = t >> 6;
    int lane = t & 63;
    int half = lane >> 5, cl = lane & 31;

    for (int rr = 0; rr < R / 2; rr++) {
        int r = rr * 2 + wv;
        int row = base + r;
        int s1 = rowptr1[row], e1 = rowptr1[row + 1];
        float4 g1 = gather_pair_bf(xsrc1, col1, s1, e1, half, cl);
        int s2 = rowptr2[row], e2 = rowptr2[row + 1];
        float4 g2 = gather_pair_bf(xsrc2, col2, s2, e2, half, cl);
        if (half == 0) {
            float4 xv = *(const float4*)(xdst + (size_t)row * CDIM + (cl << 2));
            float i1 = 1.0f / (float)max(e1 - s1, 1);
            float i2 = 1.0f / (float)max(e2 - s2, 1);
            float4 u, v;
            u.x = g1.x * i1 + xv.x; u.y = g1.y * i1 + xv.y;
            u.z = g1.z * i1 + xv.z; u.w = g1.w * i1 + xv.w;
            v.x = g2.x * i2 + xv.x; v.y = g2.y * i2 + xv.y;
            v.z = g2.z * i2 + xv.z; v.w = g2.w * i2 + xv.w;
            *(float4*)&U[r][cl << 2] = u;
            *(float4*)&V[r][cl << 2] = v;
        }
    }
    __syncthreads();

    float acc[R];
    float b = bias1[t] + bias2[t];
#pragma unroll
    for (int r = 0; r < R; r++) acc[r] = b;

    const float4* W1r = (const float4*)(W1 + (size_t)t * CDIM);
    const float4* W2r = (const float4*)(W2 + (size_t)t * CDIM);
    for (int k4 = 0; k4 < 32; k4++) {
        float4 w1 = W1r[k4];
        float4 w2 = W2r[k4];
#pragma unroll
        for (int r = 0; r < R; r++) {
            float4 u = *(const float4*)&U[r][k4 * 4];
            float4 v = *(const float4*)&V[r][k4 * 4];
            acc[r] += u.x * w1.x + u.y * w1.y + u.z * w1.z + u.w * w1.w
                    + v.x * w2.x + v.y * w2.y + v.z * w2.z + v.w * w2.w;
        }
    }

    float lw = lnw[t], lb = lnb[t];
    for (int r = 0; r < R; r++) {
        float v = acc[r];
        float s = v, s2 = v * v;
        for (int off = 32; off > 0; off >>= 1) {
            s += __shfl_down(s, off, 64);
            s2 += __shfl_down(s2, off, 64);
        }
        if (lane == 0) { red[wv][0] = s; red[wv][1] = s2; }
        __syncthreads();
        float tot = red[0][0] + red[1][0];
        float tot2 = red[0][1] + red[1][1];
        float mu = tot * (1.0f / CDIM);
        float var = tot2 * (1.0f / CDIM) - mu * mu;
        float rs = rsqrtf(var + 1e-5f);
        float o = (v - mu) * rs * lw + lb;
        float rl = fmaxf(o, 0.0f);
        size_t oi = (size_t)(base + r) * CDIM + t;
        xnext[oi] = rl;
        if (xnext_bf) xnext_bf[oi] = f2bf(rl);
        __syncthreads();
    }
}

extern "C" void kernel_launch(void* const* d_in, const int* in_sizes, int n_in,
                              void* d_out, int out_size, void* d_ws, size_t ws_size,
                              hipStream_t stream)
{
    const float* x_a      = (const float*)d_in[0];
    const float* x_b      = (const float*)d_in[1];
    const float* schema_x = (const float*)d_in[2];
    const int*   e_ab     = (const int*)d_in[3];
    const int*   e_ba     = (const int*)d_in[4];
    const int*   e_aa     = (const int*)d_in[5];
    const int*   sei      = (const int*)d_in[6];
    const float* preW     = (const float*)d_in[7];
    const float* preb     = (const float*)d_in[8];
    const float* gcnW     = (const float*)d_in[9];
    const float* gcnb     = (const float*)d_in[10];
    const float* coW      = (const float*)d_in[11];
    const float* cob      = (const float*)d_in[12];
    const float* bases    = (const float*)d_in[13];
    const float* sbias    = (const float*)d_in[14];
    const float* lnw      = (const float*)d_in[15];
    const float* lnb      = (const float*)d_in[16];

    float* out     = (float*)d_out;
    float* out_xa  = out;
    float* out_xb  = out + 6400000;
    float* out_sf  = out + 12800000;
    float* out_ori = out + 12800512;

    float* ws = (float*)d_ws;
    int*   col    = (int*)ws;
    int*   rowptr = (int*)(ws + 2400000);
    int*   pos    = (int*)(ws + 2550003);
    int*   hist   = (int*)(ws + 2700003);
    float* xa_buf = ws + 2850016;
    float* xb_buf = ws + 9250016;
    float* Wbuf   = ws + 15650016;
    float* coeffs = ws + 15748320;
    unsigned short* xa_bf0 = (unsigned short*)(ws + 15748352);
    unsigned short* xb_bf0 = (unsigned short*)(ws + 18948352);
    unsigned short* xa_bf1 = (unsigned short*)(ws + 22148352);
    unsigned short* xb_bf1 = (unsigned short*)(ws + 25348352);

    schema_kernel<<<1, 512, 0, stream>>>(schema_x, sei, preW, preb, gcnW, gcnb,
                                         coW, cob, out_sf, out_ori, coeffs);
    build_w_kernel<<<384, 256, 0, stream>>>(bases, coeffs, Wbuf);

    tobf16_kernel<<<(NA * CDIM / 4 + 255) / 256, 256, 0, stream>>>(x_a, xa_bf0, NA * CDIM);
    tobf16_kernel<<<(NB * CDIM / 4 + 255) / 256, 256, 0, stream>>>(x_b, xb_bf0, NB * CDIM);

    hipMemsetAsync(hist, 0, 3 * NN * sizeof(int), stream);
    dim3 egrid(EDGES / 256, 3);
    hist_kernel<<<egrid, 256, 0, stream>>>(e_ab, e_ba, e_aa, hist);
    scan_kernel<<<3, 1024, 0, stream>>>(hist, rowptr, pos);
    fill_kernel<<<egrid, 256, 0, stream>>>(e_ab, e_ba, e_aa, pos, col);

    const int* rp_ab = rowptr;
    const int* rp_ba = rowptr + (NN + 1);
    const int* rp_aa = rowptr + 2 * (NN + 1);
    const int* col_ab = col;
    const int* col_ba = col + EDGES;
    const int* col_aa = col + 2 * EDGES;

    for (int l = 0; l < 2; l++) {
        const float* xa_cur = (l == 0) ? x_a : xa_buf;
        const float* xb_cur = (l == 0) ? x_b : xb_buf;
        const unsigned short* xa_bf = (l == 0) ? xa_bf0 : xa_bf1;
        const unsigned short* xb_bf = (l == 0) ? xb_bf0 : xb_bf1;
        const float* Wab = Wbuf + (size_t)(l * 3 + 0) * 16384;
        const float* Wba = Wbuf + (size_t)(l * 3 + 1) * 16384;
        const float* Waa = Wbuf + (size_t)(l * 3 + 2) * 16384;
        float* xa_nxt = (l == 0) ? xa_buf : out_xa;
        float* xb_nxt = (l == 0) ? xb_buf : out_xb;
        unsigned short* xa_nbf = (l == 0) ? xa_bf1 : nullptr;
        unsigned short* xb_nbf = (l == 0) ? xb_bf1 : nullptr;

        fuse_b_kernel<<<NB / 8, 128, 0, stream>>>(
            xa_bf, xb_cur, rp_ab, col_ab, Wab,
            sbias + (size_t)(l * 3 + 0) * 128,
            lnw + (size_t)(l * 2 + 1) * 128, lnb + (size_t)(l * 2 + 1) * 128,
            xb_nxt, xb_nbf);
        fuse_a_kernel<<<NA / 8, 128, 0, stream>>>(
            xb_bf, rp_ba, col_ba, xa_bf, rp_aa, col_aa, xa_cur,
            Wba, Waa,
            sbias + (size_t)(l * 3 + 1) * 128, sbias + (size_t)(l * 3 + 2) * 128,
            lnw + (size_t)(l * 2 + 0) * 128, lnb + (size_t)(l * 2 + 0) * 128,
            xa_nxt, xa_nbf);
    }
}

// Round 6
// 929.046 us; speedup vs baseline: 2.8185x; 1.2085x over previous
//
#include <hip/hip_runtime.h>

#define NA 50000
#define NB 50000
#define NN 50000
#define CDIM 128
#define EDGES 800000
#define SS 8
#define INDIM 64
#define HDIM 64
#define NBASES 8

// ---------------------------------------------------------------------------
// Workspace layout (4-byte element offsets):
//   0         col      [3*E]      int
//   2400000   rowptr   [3*(NN+1)] int
//   2550003   pos      [3*NN]     int
//   2700003   hist     [3*NN]     int
//   2850016   xa_buf   [NA*128]   float
//   9250016   xb_buf   [NB*128]   float
//   15650016  W        [6*128*128] float (k-major packed: [k4][j][kk])
//   15748320  coeffs   [3*8]      float
//   15748352  xa_bf0   ushort[(NN+1)*128]   (row NN = zero row)
//   18948416  xb_bf0   ushort[(NN+1)*128]
//   22148480  xa_bf1   ushort[(NN+1)*128]
//   25348544  xb_bf1   ushort[(NN+1)*128]
//   28548608  end  (~114 MB)
// ---------------------------------------------------------------------------

__device__ __forceinline__ unsigned short f2bf(float f) {
    unsigned u = __float_as_uint(f);
    return (unsigned short)((u + 0x7FFFu + ((u >> 16) & 1u)) >> 16);
}

// Schema GCN + coefficient computation. One block, 512 threads.
__global__ __launch_bounds__(512) void schema_kernel(
    const float* __restrict__ schema_x, const int* __restrict__ sei,
    const float* __restrict__ preW, const float* __restrict__ preb,
    const float* __restrict__ gcnW, const float* __restrict__ gcnb,
    const float* __restrict__ coW, const float* __restrict__ cob,
    float* __restrict__ out_sf, float* __restrict__ out_ori,
    float* __restrict__ coeffs)
{
    __shared__ float h[SS][HDIM];
    __shared__ float xw[SS][HDIM];
    __shared__ float sf[SS][HDIM];
    __shared__ float deg[SS];
    __shared__ float nrm[32];
    __shared__ int es[32], ed[32];

    int t = threadIdx.x;
    int i = t >> 6, j = t & 63;

    float acc = preb[j];
    for (int k = 0; k < INDIM; k++) acc += schema_x[i * INDIM + k] * preW[j * INDIM + k];
    h[i][j] = acc;
    out_ori[i * HDIM + j] = acc;
    if (t < SS) deg[t] = 0.0f;
    __syncthreads();

    if (t < 32) {
        int s, d;
        if (t < 24) { s = sei[t]; d = sei[24 + t]; }
        else        { s = t - 24; d = t - 24; }
        es[t] = s; ed[t] = d;
        atomicAdd(&deg[d], 1.0f);
    }
    __syncthreads();
    if (t < 32) {
        nrm[t] = rsqrtf(fmaxf(deg[es[t]], 1e-12f)) * rsqrtf(fmaxf(deg[ed[t]], 1e-12f));
    }
    float a2 = 0.0f;
    for (int k = 0; k < HDIM; k++) a2 += h[i][k] * gcnW[j * HDIM + k];
    xw[i][j] = a2;
    __syncthreads();

    float o = gcnb[j];
    for (int e = 0; e < 32; e++) {
        if (ed[e] == i) o += xw[es[e]][j] * nrm[e];
    }
    float s = fmaxf(o, 0.0f);
    sf[i][j] = s;
    out_sf[i * HDIM + j] = s;
    __syncthreads();

    if (t < 24) {
        int ty = t >> 3, ii = t & 7;
        int srow = (ty == 1) ? 1 : 0;
        int drow = (ty == 0) ? 1 : 0;
        float a = cob[ii];
        for (int k = 0; k < HDIM; k++) a += sf[srow][k] * coW[ii * (2 * HDIM) + k];
        for (int k = 0; k < HDIM; k++) a += sf[drow][k] * coW[ii * (2 * HDIM) + HDIM + k];
        coeffs[ty * 8 + ii] = a;
    }
}

// W packed k-major: out[mat*16384 + (k>>2)*512 + j*4 + (k&3)] = sum_i c_i * bases[..][j][k]
__global__ __launch_bounds__(256) void build_w_kernel(
    const float* __restrict__ bases, const float* __restrict__ coeffs,
    float* __restrict__ W)
{
    int idx = blockIdx.x * blockDim.x + threadIdx.x;
    int lt = idx >> 14;
    int jk = idx & 16383;
    int j = jk >> 7, k = jk & 127;
    int l = lt / 3, ty = lt % 3;
    float acc = 0.0f;
#pragma unroll
    for (int i = 0; i < NBASES; i++)
        acc += coeffs[ty * 8 + i] * bases[((size_t)(l * NBASES + i) << 14) + jk];
    W[(lt << 14) + ((k >> 2) << 9) + (j << 2) + (k & 3)] = acc;
}

// fp32 -> bf16 table conversion (n divisible by 4)
__global__ __launch_bounds__(256) void tobf16_kernel(
    const float* __restrict__ in, unsigned short* __restrict__ out, int n)
{
    int i = (blockIdx.x * 256 + threadIdx.x) * 4;
    if (i >= n) return;
    float4 f = *(const float4*)(in + i);
    ushort4 o;
    o.x = f2bf(f.x); o.y = f2bf(f.y); o.z = f2bf(f.z); o.w = f2bf(f.w);
    *(ushort4*)(out + i) = o;
}

// zero row NN of each bf16 table (gather redirect target)
__global__ __launch_bounds__(256) void zero_rows_kernel(
    unsigned short* a0, unsigned short* b0, unsigned short* a1, unsigned short* b1)
{
    int t = threadIdx.x;
    int tab = t >> 6, w = t & 63;
    unsigned short* p = (tab == 0) ? a0 : (tab == 1) ? b0 : (tab == 2) ? a1 : b1;
    ((unsigned*)(p + (size_t)NN * CDIM))[w] = 0u;
}

// ---------------- CSR build (once per launch) -------------------------------

__global__ __launch_bounds__(256) void hist_kernel(
    const int* __restrict__ ab, const int* __restrict__ ba,
    const int* __restrict__ aa, int* __restrict__ hist)
{
    int e = blockIdx.x * 256 + threadIdx.x;
    int ty = blockIdx.y;
    if (e >= EDGES) return;
    const int* ei = (ty == 0) ? ab : (ty == 1) ? ba : aa;
    atomicAdd(&hist[ty * NN + ei[EDGES + e]], 1);
}

__global__ __launch_bounds__(1024) void scan_kernel(
    const int* __restrict__ hist, int* __restrict__ rowptr, int* __restrict__ pos)
{
    const int CH = 49;
    int ty = blockIdx.x;
    const int* h = hist + ty * NN;
    int* rp = rowptr + ty * (NN + 1);
    int* ps = pos + ty * NN;

    __shared__ int sbuf[1024];
    int t = threadIdx.x;
    int start = t * CH;
    int end = min(start + CH, NN);

    int sum = 0;
    for (int i = start; i < end; i++) sum += h[i];
    sbuf[t] = sum;
    __syncthreads();
    for (int off = 1; off < 1024; off <<= 1) {
        int v = (t >= off) ? sbuf[t - off] : 0;
        __syncthreads();
        sbuf[t] += v;
        __syncthreads();
    }
    int run = sbuf[t] - sum;
    for (int i = start; i < end; i++) {
        rp[i] = run; ps[i] = run;
        run += h[i];
    }
    if (t == 1023) rp[NN] = run;
}

__global__ __launch_bounds__(256) void fill_kernel(
    const int* __restrict__ ab, const int* __restrict__ ba,
    const int* __restrict__ aa, int* __restrict__ pos, int* __restrict__ col)
{
    int e = blockIdx.x * 256 + threadIdx.x;
    int ty = blockIdx.y;
    if (e >= EDGES) return;
    const int* ei = (ty == 0) ? ab : (ty == 1) ? ba : aa;
    int src = ei[e], dst = ei[EDGES + e];
    int slot = atomicAdd(&pos[ty * NN + dst], 1);
    col[(size_t)ty * EDGES + slot] = src;
}

// ---------------- fused gather + (mean + x)@W^T + bias -> LN -> ReLU --------

// Wave-wide gather, 2 edges per load instruction (lane = 32*half + cl; lane
// loads uint2 = 4 bf16 channels of edge slot s+2j+half). All 16 pair-indices
// (32 edge slots) preloaded in one batch; value loads in <=2 wave-uniform
// batches; slots >= e redirect to the zero row NN (maskless accumulate).
__device__ __forceinline__ float4 gather2_bf(
    const unsigned short* __restrict__ xsrc, const int* __restrict__ col,
    int s, int e, int half, int off)
{
    float4 g = {0.f, 0.f, 0.f, 0.f};
    int n = e - s;
    if (n > 0) {
        int cs[16];
#pragma unroll
        for (int j = 0; j < 16; j++) {
            int slot = s + 2 * j + half;
            int cc = col[min(slot, e - 1)];
            cs[j] = (slot < e) ? cc : NN;
        }
        uint2 v[16];
#pragma unroll
        for (int j = 0; j < 8; j++)
            v[j] = *(const uint2*)(xsrc + (size_t)cs[j] * CDIM + off);
        if (n > 16) {
#pragma unroll
            for (int j = 8; j < 16; j++)
                v[j] = *(const uint2*)(xsrc + (size_t)cs[j] * CDIM + off);
        } else {
#pragma unroll
            for (int j = 8; j < 16; j++) v[j] = make_uint2(0u, 0u);
        }
#pragma unroll
        for (int j = 0; j < 16; j++) {
            g.x += __uint_as_float(v[j].x << 16);
            g.y += __uint_as_float(v[j].x & 0xffff0000u);
            g.z += __uint_as_float(v[j].y << 16);
            g.w += __uint_as_float(v[j].y & 0xffff0000u);
        }
        // rare tail (n > 32): Poisson(16) makes this ~1e-4 of rows
        for (int b2 = s + 32; b2 < e; b2 += 16) {
#pragma unroll
            for (int j = 0; j < 8; j++) {
                int slot = b2 + 2 * j + half;
                int cc = col[min(slot, e - 1)];
                int id = (slot < e) ? cc : NN;
                uint2 vv = *(const uint2*)(xsrc + (size_t)id * CDIM + off);
                g.x += __uint_as_float(vv.x << 16);
                g.y += __uint_as_float(vv.x & 0xffff0000u);
                g.z += __uint_as_float(vv.y << 16);
                g.w += __uint_as_float(vv.y & 0xffff0000u);
            }
        }
    }
    g.x += __shfl_xor(g.x, 32, 64);
    g.y += __shfl_xor(g.y, 32, 64);
    g.z += __shfl_xor(g.z, 32, 64);
    g.w += __shfl_xor(g.w, 32, 64);
    return g;
}

// b-side: mean(bf16 x_a[in-edges]) + x_b, @W^T + bias -> LN -> ReLU
__global__ __launch_bounds__(128) void fuse_b_kernel(
    const unsigned short* __restrict__ xsrc, const float* __restrict__ xdst,
    const int* __restrict__ rowptr, const int* __restrict__ col,
    const float* __restrict__ W, const float* __restrict__ bias,
    const float* __restrict__ lnw, const float* __restrict__ lnb,
    float* __restrict__ xnext, unsigned short* __restrict__ xnext_bf)
{
    const int R = 8;
    __shared__ __align__(16) float U[R][CDIM];
    int t = threadIdx.x;
    int base = blockIdx.x * R;
    int wv = t >> 6;
    int lane = t & 63;
    int half = lane >> 5, cl = lane & 31;
    int off = cl << 2;

    for (int rr = 0; rr < R / 2; rr++) {
        int r = rr * 2 + wv;
        int row = base + r;
        int s = rowptr[row], e = rowptr[row + 1];
        float4 g = gather2_bf(xsrc, col, s, e, half, off);
        if (half == 0) {
            float inv = 1.0f / (float)max(e - s, 1);
            float4 xv = *(const float4*)(xdst + (size_t)row * CDIM + off);
            float4 u;
            u.x = g.x * inv + xv.x; u.y = g.y * inv + xv.y;
            u.z = g.z * inv + xv.z; u.w = g.w * inv + xv.w;
            *(float4*)&U[r][off] = u;
        }
    }
    __syncthreads();

    float acc[R];
    float b = bias[t];
#pragma unroll
    for (int r = 0; r < R; r++) acc[r] = b;

    // W packed k-major: Wp4[k4*128 + t] = {W[t][4k4..4k4+3]} -> coalesced
    const float4* Wp4 = (const float4*)W;
    for (int k4 = 0; k4 < 32; k4++) {
        float4 w = Wp4[k4 * 128 + t];
#pragma unroll
        for (int r = 0; r < R; r++) {
            float4 u = *(const float4*)&U[r][k4 * 4];
            acc[r] += u.x * w.x + u.y * w.y + u.z * w.z + u.w * w.w;
        }
    }

    // epilogue: stage acc through LDS (2 barriers total), wave-parallel LN
    __syncthreads();
#pragma unroll
    for (int r = 0; r < R; r++) U[r][t] = acc[r];
    __syncthreads();

    float lw0 = lnw[lane], lw1 = lnw[lane + 64];
    float lb0 = lnb[lane], lb1 = lnb[lane + 64];
    for (int rr = 0; rr < R / 2; rr++) {
        int r = rr * 2 + wv;
        int row = base + r;
        float v0 = U[r][lane], v1 = U[r][lane + 64];
        float s = v0 + v1, s2 = v0 * v0 + v1 * v1;
#pragma unroll
        for (int o2 = 32; o2 > 0; o2 >>= 1) {
            s  += __shfl_xor(s,  o2, 64);
            s2 += __shfl_xor(s2, o2, 64);
        }
        float mu = s * (1.0f / CDIM);
        float var = s2 * (1.0f / CDIM) - mu * mu;
        float rs = rsqrtf(var + 1e-5f);
        float o0 = fmaxf((v0 - mu) * rs * lw0 + lb0, 0.0f);
        float o1 = fmaxf((v1 - mu) * rs * lw1 + lb1, 0.0f);
        size_t oi = (size_t)row * CDIM;
        xnext[oi + lane] = o0;
        xnext[oi + lane + 64] = o1;
        if (xnext_bf) {
            xnext_bf[oi + lane] = f2bf(o0);
            xnext_bf[oi + lane + 64] = f2bf(o1);
        }
    }
}

// a-side: (mean_ba(bf x_b)+x_a)@W1^T + (mean_aa(bf x_a)+x_a)@W2^T + b1+b2 -> LN -> ReLU
__global__ __launch_bounds__(128) void fuse_a_kernel(
    const unsigned short* __restrict__ xsrc1, const int* __restrict__ rowptr1, const int* __restrict__ col1,
    const unsigned short* __restrict__ xsrc2, const int* __restrict__ rowptr2, const int* __restrict__ col2,
    const float* __restrict__ xdst,
    const float* __restrict__ W1, const float* __restrict__ W2,
    const float* __restrict__ bias1, const float* __restrict__ bias2,
    const float* __restrict__ lnw, const float* __restrict__ lnb,
    float* __restrict__ xnext, unsigned short* __restrict__ xnext_bf)
{
    const int R = 8;
    __shared__ __align__(16) float U[R][CDIM];
    __shared__ __align__(16) float V[R][CDIM];
    int t = threadIdx.x;
    int base = blockIdx.x * R;
    int wv = t >> 6;
    int lane = t & 63;
    int half = lane >> 5, cl = lane & 31;
    int off = cl << 2;

    for (int rr = 0; rr < R / 2; rr++) {
        int r = rr * 2 + wv;
        int row = base + r;
        int s1 = rowptr1[row], e1 = rowptr1[row + 1];
        float4 g1 = gather2_bf(xsrc1, col1, s1, e1, half, off);
        int s2 = rowptr2[row], e2 = rowptr2[row + 1];
        float4 g2 = gather2_bf(xsrc2, col2, s2, e2, half, off);
        if (half == 0) {
            float4 xv = *(const float4*)(xdst + (size_t)row * CDIM + off);
            float i1 = 1.0f / (float)max(e1 - s1, 1);
            float i2 = 1.0f / (float)max(e2 - s2, 1);
            float4 u, v;
            u.x = g1.x * i1 + xv.x; u.y = g1.y * i1 + xv.y;
            u.z = g1.z * i1 + xv.z; u.w = g1.w * i1 + xv.w;
            v.x = g2.x * i2 + xv.x; v.y = g2.y * i2 + xv.y;
            v.z = g2.z * i2 + xv.z; v.w = g2.w * i2 + xv.w;
            *(float4*)&U[r][off] = u;
            *(float4*)&V[r][off] = v;
        }
    }
    __syncthreads();

    float acc[R];
    float b = bias1[t] + bias2[t];
#pragma unroll
    for (int r = 0; r < R; r++) acc[r] = b;

    const float4* W1p = (const float4*)W1;
    const float4* W2p = (const float4*)W2;
    for (int k4 = 0; k4 < 32; k4++) {
        float4 w1 = W1p[k4 * 128 + t];
        float4 w2 = W2p[k4 * 128 + t];
#pragma unroll
        for (int r = 0; r < R; r++) {
            float4 u = *(const float4*)&U[r][k4 * 4];
            float4 v = *(const float4*)&V[r][k4 * 4];
            acc[r] += u.x * w1.x + u.y * w1.y + u.z * w1.z + u.w * w1.w
                    + v.x * w2.x + v.y * w2.y + v.z * w2.z + v.w * w2.w;
        }
    }

    __syncthreads();
#pragma unroll
    for (int r = 0; r < R; r++) U[r][t] = acc[r];
    __syncthreads();

    float lw0 = lnw[lane], lw1 = lnw[lane + 64];
    float lb0 = lnb[lane], lb1 = lnb[lane + 64];
    for (int rr = 0; rr < R / 2; rr++) {
        int r = rr * 2 + wv;
        int row = base + r;
        float v0 = U[r][lane], v1 = U[r][lane + 64];
        float s = v0 + v1, s2 = v0 * v0 + v1 * v1;
#pragma unroll
        for (int o2 = 32; o2 > 0; o2 >>= 1) {
            s  += __shfl_xor(s,  o2, 64);
            s2 += __shfl_xor(s2, o2, 64);
        }
        float mu = s * (1.0f / CDIM);
        float var = s2 * (1.0f / CDIM) - mu * mu;
        float rs = rsqrtf(var + 1e-5f);
        float o0 = fmaxf((v0 - mu) * rs * lw0 + lb0, 0.0f);
        float o1 = fmaxf((v1 - mu) * rs * lw1 + lb1, 0.0f);
        size_t oi = (size_t)row * CDIM;
        xnext[oi + lane] = o0;
        xnext[oi + lane + 64] = o1;
        if (xnext_bf) {
            xnext_bf[oi + lane] = f2bf(o0);
            xnext_bf[oi + lane + 64] = f2bf(o1);
        }
    }
}

extern "C" void kernel_launch(void* const* d_in, const int* in_sizes, int n_in,
                              void* d_out, int out_size, void* d_ws, size_t ws_size,
                              hipStream_t stream)
{
    const float* x_a      = (const float*)d_in[0];
    const float* x_b      = (const float*)d_in[1];
    const float* schema_x = (const float*)d_in[2];
    const int*   e_ab     = (const int*)d_in[3];
    const int*   e_ba     = (const int*)d_in[4];
    const int*   e_aa     = (const int*)d_in[5];
    const int*   sei      = (const int*)d_in[6];
    const float* preW     = (const float*)d_in[7];
    const float* preb     = (const float*)d_in[8];
    const float* gcnW     = (const float*)d_in[9];
    const float* gcnb     = (const float*)d_in[10];
    const float* coW      = (const float*)d_in[11];
    const float* cob      = (const float*)d_in[12];
    const float* bases    = (const float*)d_in[13];
    const float* sbias    = (const float*)d_in[14];
    const float* lnw      = (const float*)d_in[15];
    const float* lnb      = (const float*)d_in[16];

    float* out     = (float*)d_out;
    float* out_xa  = out;
    float* out_xb  = out + 6400000;
    float* out_sf  = out + 12800000;
    float* out_ori = out + 12800512;

    float* ws = (float*)d_ws;
    int*   col    = (int*)ws;
    int*   rowptr = (int*)(ws + 2400000);
    int*   pos    = (int*)(ws + 2550003);
    int*   hist   = (int*)(ws + 2700003);
    float* xa_buf = ws + 2850016;
    float* xb_buf = ws + 9250016;
    float* Wbuf   = ws + 15650016;
    float* coeffs = ws + 15748320;
    unsigned short* xa_bf0 = (unsigned short*)(ws + 15748352);
    unsigned short* xb_bf0 = (unsigned short*)(ws + 18948416);
    unsigned short* xa_bf1 = (unsigned short*)(ws + 22148480);
    unsigned short* xb_bf1 = (unsigned short*)(ws + 25348544);

    schema_kernel<<<1, 512, 0, stream>>>(schema_x, sei, preW, preb, gcnW, gcnb,
                                         coW, cob, out_sf, out_ori, coeffs);
    build_w_kernel<<<384, 256, 0, stream>>>(bases, coeffs, Wbuf);

    tobf16_kernel<<<(NA * CDIM / 4 + 255) / 256, 256, 0, stream>>>(x_a, xa_bf0, NA * CDIM);
    tobf16_kernel<<<(NB * CDIM / 4 + 255) / 256, 256, 0, stream>>>(x_b, xb_bf0, NB * CDIM);
    zero_rows_kernel<<<1, 256, 0, stream>>>(xa_bf0, xb_bf0, xa_bf1, xb_bf1);

    hipMemsetAsync(hist, 0, 3 * NN * sizeof(int), stream);
    dim3 egrid(EDGES / 256, 3);
    hist_kernel<<<egrid, 256, 0, stream>>>(e_ab, e_ba, e_aa, hist);
    scan_kernel<<<3, 1024, 0, stream>>>(hist, rowptr, pos);
    fill_kernel<<<egrid, 256, 0, stream>>>(e_ab, e_ba, e_aa, pos, col);

    const int* rp_ab = rowptr;
    const int* rp_ba = rowptr + (NN + 1);
    const int* rp_aa = rowptr + 2 * (NN + 1);
    const int* col_ab = col;
    const int* col_ba = col + EDGES;
    const int* col_aa = col + 2 * EDGES;

    for (int l = 0; l < 2; l++) {
        const float* xa_cur = (l == 0) ? x_a : xa_buf;
        const float* xb_cur = (l == 0) ? x_b : xb_buf;
        const unsigned short* xa_bf = (l == 0) ? xa_bf0 : xa_bf1;
        const unsigned short* xb_bf = (l == 0) ? xb_bf0 : xb_bf1;
        const float* Wab = Wbuf + (size_t)(l * 3 + 0) * 16384;
        const float* Wba = Wbuf + (size_t)(l * 3 + 1) * 16384;
        const float* Waa = Wbuf + (size_t)(l * 3 + 2) * 16384;
        float* xa_nxt = (l == 0) ? xa_buf : out_xa;
        float* xb_nxt = (l == 0) ? xb_buf : out_xb;
        unsigned short* xa_nbf = (l == 0) ? xa_bf1 : nullptr;
        unsigned short* xb_nbf = (l == 0) ? xb_bf1 : nullptr;

        fuse_b_kernel<<<NB / 8, 128, 0, stream>>>(
            xa_bf, xb_cur, rp_ab, col_ab, Wab,
            sbias + (size_t)(l * 3 + 0) * 128,
            lnw + (size_t)(l * 2 + 1) * 128, lnb + (size_t)(l * 2 + 1) * 128,
            xb_nxt, xb_nbf);
        fuse_a_kernel<<<NA / 8, 128, 0, stream>>>(
            xb_bf, rp_ba, col_ba, xa_bf, rp_aa, col_aa, xa_cur,
            Wba, Waa,
            sbias + (size_t)(l * 3 + 1) * 128, sbias + (size_t)(l * 3 + 2) * 128,
            lnw + (size_t)(l * 2 + 0) * 128, lnb + (size_t)(l * 2 + 0) * 128,
            xa_nxt, xa_nbf);
    }
}

// Round 7
// 657.316 us; speedup vs baseline: 3.9837x; 1.4134x over previous
//
#include <hip/hip_runtime.h>

#define NA 50000
#define NB 50000
#define NN 50000
#define CDIM 128
#define EDGES 800000
#define SS 8
#define INDIM 64
#define HDIM 64
#define NBASES 8
#define NBUCK 98   // dst buckets of 512 rows (50176 >= 50000)
#define BSH 9

// ---------------------------------------------------------------------------
// Workspace layout (4-byte element offsets):
//   0         col      [3*E]        int
//   2400000   rowptr   [3*(NN+1)]   int
//   2550016   buf      [3*E]        uint (bucket-partitioned packed edges)
//   4950016   bcnt     [3*98]       int
//   4950320   boff     [3*99]       int
//   4950624   bcur     [3*98]       int
//   4950928   xa_buf   [NA*128]     float
//   11350928  xb_buf   [NB*128]     float
//   17750928  W        [6*128*128]  float (k-major packed)
//   17849232  coeffs   [3*8]        float
//   17849264  xa_bf0   ushort[(NN+1)*128]   (row NN = zero row)
//   21049328  xb_bf0   ushort[(NN+1)*128]
//   24249392  xa_bf1   ushort[(NN+1)*128]
//   27449456  xb_bf1   ushort[(NN+1)*128]
//   30649520  end (~123 MB)
// ---------------------------------------------------------------------------

__device__ __forceinline__ unsigned short f2bf(float f) {
    unsigned u = __float_as_uint(f);
    return (unsigned short)((u + 0x7FFFu + ((u >> 16) & 1u)) >> 16);
}

// Schema GCN + coefficient computation. One block, 512 threads.
__global__ __launch_bounds__(512) void schema_kernel(
    const float* __restrict__ schema_x, const int* __restrict__ sei,
    const float* __restrict__ preW, const float* __restrict__ preb,
    const float* __restrict__ gcnW, const float* __restrict__ gcnb,
    const float* __restrict__ coW, const float* __restrict__ cob,
    float* __restrict__ out_sf, float* __restrict__ out_ori,
    float* __restrict__ coeffs)
{
    __shared__ float h[SS][HDIM];
    __shared__ float xw[SS][HDIM];
    __shared__ float sf[SS][HDIM];
    __shared__ float deg[SS];
    __shared__ float nrm[32];
    __shared__ int es[32], ed[32];

    int t = threadIdx.x;
    int i = t >> 6, j = t & 63;

    float acc = preb[j];
    for (int k = 0; k < INDIM; k++) acc += schema_x[i * INDIM + k] * preW[j * INDIM + k];
    h[i][j] = acc;
    out_ori[i * HDIM + j] = acc;
    if (t < SS) deg[t] = 0.0f;
    __syncthreads();

    if (t < 32) {
        int s, d;
        if (t < 24) { s = sei[t]; d = sei[24 + t]; }
        else        { s = t - 24; d = t - 24; }
        es[t] = s; ed[t] = d;
        atomicAdd(&deg[d], 1.0f);
    }
    __syncthreads();
    if (t < 32) {
        nrm[t] = rsqrtf(fmaxf(deg[es[t]], 1e-12f)) * rsqrtf(fmaxf(deg[ed[t]], 1e-12f));
    }
    float a2 = 0.0f;
    for (int k = 0; k < HDIM; k++) a2 += h[i][k] * gcnW[j * HDIM + k];
    xw[i][j] = a2;
    __syncthreads();

    float o = gcnb[j];
    for (int e = 0; e < 32; e++) {
        if (ed[e] == i) o += xw[es[e]][j] * nrm[e];
    }
    float s = fmaxf(o, 0.0f);
    sf[i][j] = s;
    out_sf[i * HDIM + j] = s;
    __syncthreads();

    if (t < 24) {
        int ty = t >> 3, ii = t & 7;
        int srow = (ty == 1) ? 1 : 0;
        int drow = (ty == 0) ? 1 : 0;
        float a = cob[ii];
        for (int k = 0; k < HDIM; k++) a += sf[srow][k] * coW[ii * (2 * HDIM) + k];
        for (int k = 0; k < HDIM; k++) a += sf[drow][k] * coW[ii * (2 * HDIM) + HDIM + k];
        coeffs[ty * 8 + ii] = a;
    }
}

// W packed k-major: out[mat*16384 + (k>>2)*512 + j*4 + (k&3)]
__global__ __launch_bounds__(256) void build_w_kernel(
    const float* __restrict__ bases, const float* __restrict__ coeffs,
    float* __restrict__ W)
{
    int idx = blockIdx.x * blockDim.x + threadIdx.x;
    int lt = idx >> 14;
    int jk = idx & 16383;
    int j = jk >> 7, k = jk & 127;
    int l = lt / 3, ty = lt % 3;
    float acc = 0.0f;
#pragma unroll
    for (int i = 0; i < NBASES; i++)
        acc += coeffs[ty * 8 + i] * bases[((size_t)(l * NBASES + i) << 14) + jk];
    W[(lt << 14) + ((k >> 2) << 9) + (j << 2) + (k & 3)] = acc;
}

__global__ __launch_bounds__(256) void tobf16_kernel(
    const float* __restrict__ in, unsigned short* __restrict__ out, int n)
{
    int i = (blockIdx.x * 256 + threadIdx.x) * 4;
    if (i >= n) return;
    float4 f = *(const float4*)(in + i);
    ushort4 o;
    o.x = f2bf(f.x); o.y = f2bf(f.y); o.z = f2bf(f.z); o.w = f2bf(f.w);
    *(ushort4*)(out + i) = o;
}

__global__ __launch_bounds__(256) void zero_rows_kernel(
    unsigned short* a0, unsigned short* b0, unsigned short* a1, unsigned short* b1)
{
    int t = threadIdx.x;
    int tab = t >> 6, w = t & 63;
    unsigned short* p = (tab == 0) ? a0 : (tab == 1) ? b0 : (tab == 2) ? a1 : b1;
    ((unsigned*)(p + (size_t)NN * CDIM))[w] = 0u;
}

// ---------------- locality-aware CSR build (once per launch) ----------------

// count edges per (type, dst>>9)
__global__ __launch_bounds__(256) void bucket_count_kernel(
    const int* __restrict__ ab, const int* __restrict__ ba,
    const int* __restrict__ aa, int* __restrict__ bcnt)
{
    __shared__ int h[NBUCK];
    int t = threadIdx.x;
    int ty = blockIdx.y;
    const int* ei = (ty == 0) ? ab : (ty == 1) ? ba : aa;
    if (t < NBUCK) h[t] = 0;
    __syncthreads();
    int cb = blockIdx.x * 4096;
    int en = min(cb + 4096, EDGES);
    for (int e = cb + t; e < en; e += 256)
        atomicAdd(&h[ei[EDGES + e] >> BSH], 1);
    __syncthreads();
    if (t < NBUCK) atomicAdd(&bcnt[ty * NBUCK + t], h[t]);
}

// tiny exclusive scan of 98 bucket counts per type -> boff, bcur
__global__ __launch_bounds__(32) void bucket_scan_kernel(
    const int* __restrict__ bcnt, int* __restrict__ boff, int* __restrict__ bcur)
{
    int t = threadIdx.x;
    if (t < 3) {
        int run = 0;
        for (int i = 0; i < NBUCK; i++) {
            int c = bcnt[t * NBUCK + i];
            boff[t * (NBUCK + 1) + i] = run;
            bcur[t * NBUCK + i] = run;
            run += c;
        }
        boff[t * (NBUCK + 1) + NBUCK] = run;  // == EDGES
    }
}

// partition edges into bucket regions; per-block contiguous runs -> coalesced
__global__ __launch_bounds__(256) void bucket_partition_kernel(
    const int* __restrict__ ab, const int* __restrict__ ba,
    const int* __restrict__ aa, int* __restrict__ bcur,
    unsigned* __restrict__ buf)
{
    __shared__ int h[NBUCK];
    __shared__ int basearr[NBUCK];
    __shared__ int cur[NBUCK];
    int t = threadIdx.x;
    int ty = blockIdx.y;
    const int* ei = (ty == 0) ? ab : (ty == 1) ? ba : aa;
    if (t < NBUCK) h[t] = 0;
    __syncthreads();
    int cb = blockIdx.x * 4096;
    int en = min(cb + 4096, EDGES);
    for (int e = cb + t; e < en; e += 256)
        atomicAdd(&h[ei[EDGES + e] >> BSH], 1);
    __syncthreads();
    if (t < NBUCK) {
        basearr[t] = atomicAdd(&bcur[ty * NBUCK + t], h[t]);
        cur[t] = 0;
    }
    __syncthreads();
    for (int e = cb + t; e < en; e += 256) {
        int src = ei[e], dst = ei[EDGES + e];
        int b = dst >> BSH;
        int r = atomicAdd(&cur[b], 1);
        buf[(size_t)ty * EDGES + basearr[b] + r] =
            ((unsigned)(dst & 511) << 16) | (unsigned)src;
    }
}

// per bucket: per-row counts -> rowptr, then scatter src ids into the bucket's
// ~33 KB col window (single block, single XCD -> L2-resident, no amplification)
__global__ __launch_bounds__(256) void bucket_scatter_kernel(
    const unsigned* __restrict__ buf, const int* __restrict__ boff,
    int* __restrict__ rowptr, int* __restrict__ col)
{
    __shared__ int cnt[512];
    __shared__ int part[256];
    int t = threadIdx.x;
    int b = blockIdx.x, ty = blockIdx.y;
    int nstart = boff[ty * (NBUCK + 1) + b];
    int nend   = boff[ty * (NBUCK + 1) + b + 1];
    int n = nend - nstart;
    cnt[t] = 0; cnt[t + 256] = 0;
    __syncthreads();
    const unsigned* bb = buf + (size_t)ty * EDGES + nstart;
    for (int i = t; i < n; i += 256)
        atomicAdd(&cnt[bb[i] >> 16], 1);
    __syncthreads();
    int a0 = cnt[2 * t], a1 = cnt[2 * t + 1];
    int s = a0 + a1;
    part[t] = s;
    __syncthreads();
    for (int off = 1; off < 256; off <<= 1) {
        int v = (t >= off) ? part[t - off] : 0;
        __syncthreads();
        part[t] += v;
        __syncthreads();
    }
    int excl = part[t] - s;
    int p0 = excl, p1 = excl + a0;
    cnt[2 * t] = p0; cnt[2 * t + 1] = p1;   // cursors (all cnt reads done)
    int row0 = (b << BSH) + 2 * t;
    int rbase = ty * (NN + 1);
    if (row0 < NN)     rowptr[rbase + row0] = nstart + p0;
    if (row0 + 1 < NN) rowptr[rbase + row0 + 1] = nstart + p1;
    if (b == NBUCK - 1 && t == 255) rowptr[rbase + NN] = EDGES;
    __syncthreads();
    int* cc = col + (size_t)ty * EDGES + nstart;
    for (int i = t; i < n; i += 256) {
        unsigned pk = bb[i];
        int r = atomicAdd(&cnt[pk >> 16], 1);
        cc[r] = (int)(pk & 0xFFFFu);
    }
}

// ---------------- fused gather + (mean + x)@W^T + bias -> LN -> ReLU --------

__device__ __forceinline__ float4 gather2_bf(
    const unsigned short* __restrict__ xsrc, const int* __restrict__ col,
    int s, int e, int half, int off)
{
    float4 g = {0.f, 0.f, 0.f, 0.f};
    int n = e - s;
    if (n > 0) {
        int cs[16];
#pragma unroll
        for (int j = 0; j < 16; j++) {
            int slot = s + 2 * j + half;
            int cc = col[min(slot, e - 1)];
            cs[j] = (slot < e) ? cc : NN;
        }
        uint2 v[16];
#pragma unroll
        for (int j = 0; j < 8; j++)
            v[j] = *(const uint2*)(xsrc + (size_t)cs[j] * CDIM + off);
        if (n > 16) {
#pragma unroll
            for (int j = 8; j < 16; j++)
                v[j] = *(const uint2*)(xsrc + (size_t)cs[j] * CDIM + off);
        } else {
#pragma unroll
            for (int j = 8; j < 16; j++) v[j] = make_uint2(0u, 0u);
        }
#pragma unroll
        for (int j = 0; j < 16; j++) {
            g.x += __uint_as_float(v[j].x << 16);
            g.y += __uint_as_float(v[j].x & 0xffff0000u);
            g.z += __uint_as_float(v[j].y << 16);
            g.w += __uint_as_float(v[j].y & 0xffff0000u);
        }
        for (int b2 = s + 32; b2 < e; b2 += 16) {
#pragma unroll
            for (int j = 0; j < 8; j++) {
                int slot = b2 + 2 * j + half;
                int cc = col[min(slot, e - 1)];
                int id = (slot < e) ? cc : NN;
                uint2 vv = *(const uint2*)(xsrc + (size_t)id * CDIM + off);
                g.x += __uint_as_float(vv.x << 16);
                g.y += __uint_as_float(vv.x & 0xffff0000u);
                g.z += __uint_as_float(vv.y << 16);
                g.w += __uint_as_float(vv.y & 0xffff0000u);
            }
        }
    }
    g.x += __shfl_xor(g.x, 32, 64);
    g.y += __shfl_xor(g.y, 32, 64);
    g.z += __shfl_xor(g.z, 32, 64);
    g.w += __shfl_xor(g.w, 32, 64);
    return g;
}

__global__ __launch_bounds__(128) void fuse_b_kernel(
    const unsigned short* __restrict__ xsrc, const float* __restrict__ xdst,
    const int* __restrict__ rowptr, const int* __restrict__ col,
    const float* __restrict__ W, const float* __restrict__ bias,
    const float* __restrict__ lnw, const float* __restrict__ lnb,
    float* __restrict__ xnext, unsigned short* __restrict__ xnext_bf)
{
    const int R = 8;
    __shared__ __align__(16) float U[R][CDIM];
    int t = threadIdx.x;
    int base = blockIdx.x * R;
    int wv = t >> 6;
    int lane = t & 63;
    int half = lane >> 5, cl = lane & 31;
    int off = cl << 2;

    for (int rr = 0; rr < R / 2; rr++) {
        int r = rr * 2 + wv;
        int row = base + r;
        int s = rowptr[row], e = rowptr[row + 1];
        float4 g = gather2_bf(xsrc, col, s, e, half, off);
        if (half == 0) {
            float inv = 1.0f / (float)max(e - s, 1);
            float4 xv = *(const float4*)(xdst + (size_t)row * CDIM + off);
            float4 u;
            u.x = g.x * inv + xv.x; u.y = g.y * inv + xv.y;
            u.z = g.z * inv + xv.z; u.w = g.w * inv + xv.w;
            *(float4*)&U[r][off] = u;
        }
    }
    __syncthreads();

    float acc[R];
    float b = bias[t];
#pragma unroll
    for (int r = 0; r < R; r++) acc[r] = b;

    const float4* Wp4 = (const float4*)W;
    for (int k4 = 0; k4 < 32; k4++) {
        float4 w = Wp4[k4 * 128 + t];
#pragma unroll
        for (int r = 0; r < R; r++) {
            float4 u = *(const float4*)&U[r][k4 * 4];
            acc[r] += u.x * w.x + u.y * w.y + u.z * w.z + u.w * w.w;
        }
    }

    __syncthreads();
#pragma unroll
    for (int r = 0; r < R; r++) U[r][t] = acc[r];
    __syncthreads();

    float lw0 = lnw[lane], lw1 = lnw[lane + 64];
    float lb0 = lnb[lane], lb1 = lnb[lane + 64];
    for (int rr = 0; rr < R / 2; rr++) {
        int r = rr * 2 + wv;
        int row = base + r;
        float v0 = U[r][lane], v1 = U[r][lane + 64];
        float s = v0 + v1, s2 = v0 * v0 + v1 * v1;
#pragma unroll
        for (int o2 = 32; o2 > 0; o2 >>= 1) {
            s  += __shfl_xor(s,  o2, 64);
            s2 += __shfl_xor(s2, o2, 64);
        }
        float mu = s * (1.0f / CDIM);
        float var = s2 * (1.0f / CDIM) - mu * mu;
        float rs = rsqrtf(var + 1e-5f);
        float o0 = fmaxf((v0 - mu) * rs * lw0 + lb0, 0.0f);
        float o1 = fmaxf((v1 - mu) * rs * lw1 + lb1, 0.0f);
        size_t oi = (size_t)row * CDIM;
        xnext[oi + lane] = o0;
        xnext[oi + lane + 64] = o1;
        if (xnext_bf) {
            xnext_bf[oi + lane] = f2bf(o0);
            xnext_bf[oi + lane + 64] = f2bf(o1);
        }
    }
}

__global__ __launch_bounds__(128) void fuse_a_kernel(
    const unsigned short* __restrict__ xsrc1, const int* __restrict__ rowptr1, const int* __restrict__ col1,
    const unsigned short* __restrict__ xsrc2, const int* __restrict__ rowptr2, const int* __restrict__ col2,
    const float* __restrict__ xdst,
    const float* __restrict__ W1, const float* __restrict__ W2,
    const float* __restrict__ bias1, const float* __restrict__ bias2,
    const float* __restrict__ lnw, const float* __restrict__ lnb,
    float* __restrict__ xnext, unsigned short* __restrict__ xnext_bf)
{
    const int R = 8;
    __shared__ __align__(16) float U[R][CDIM];
    __shared__ __align__(16) float V[R][CDIM];
    int t = threadIdx.x;
    int base = blockIdx.x * R;
    int wv = t >> 6;
    int lane = t & 63;
    int half = lane >> 5, cl = lane & 31;
    int off = cl << 2;

    for (int rr = 0; rr < R / 2; rr++) {
        int r = rr * 2 + wv;
        int row = base + r;
        int s1 = rowptr1[row], e1 = rowptr1[row + 1];
        float4 g1 = gather2_bf(xsrc1, col1, s1, e1, half, off);
        int s2 = rowptr2[row], e2 = rowptr2[row + 1];
        float4 g2 = gather2_bf(xsrc2, col2, s2, e2, half, off);
        if (half == 0) {
            float4 xv = *(const float4*)(xdst + (size_t)row * CDIM + off);
            float i1 = 1.0f / (float)max(e1 - s1, 1);
            float i2 = 1.0f / (float)max(e2 - s2, 1);
            float4 u, v;
            u.x = g1.x * i1 + xv.x; u.y = g1.y * i1 + xv.y;
            u.z = g1.z * i1 + xv.z; u.w = g1.w * i1 + xv.w;
            v.x = g2.x * i2 + xv.x; v.y = g2.y * i2 + xv.y;
            v.z = g2.z * i2 + xv.z; v.w = g2.w * i2 + xv.w;
            *(float4*)&U[r][off] = u;
            *(float4*)&V[r][off] = v;
        }
    }
    __syncthreads();

    float acc[R];
    float b = bias1[t] + bias2[t];
#pragma unroll
    for (int r = 0; r < R; r++) acc[r] = b;

    const float4* W1p = (const float4*)W1;
    const float4* W2p = (const float4*)W2;
    for (int k4 = 0; k4 < 32; k4++) {
        float4 w1 = W1p[k4 * 128 + t];
        float4 w2 = W2p[k4 * 128 + t];
#pragma unroll
        for (int r = 0; r < R; r++) {
            float4 u = *(const float4*)&U[r][k4 * 4];
            float4 v = *(const float4*)&V[r][k4 * 4];
            acc[r] += u.x * w1.x + u.y * w1.y + u.z * w1.z + u.w * w1.w
                    + v.x * w2.x + v.y * w2.y + v.z * w2.z + v.w * w2.w;
        }
    }

    __syncthreads();
#pragma unroll
    for (int r = 0; r < R; r++) U[r][t] = acc[r];
    __syncthreads();

    float lw0 = lnw[lane], lw1 = lnw[lane + 64];
    float lb0 = lnb[lane], lb1 = lnb[lane + 64];
    for (int rr = 0; rr < R / 2; rr++) {
        int r = rr * 2 + wv;
        int row = base + r;
        float v0 = U[r][lane], v1 = U[r][lane + 64];
        float s = v0 + v1, s2 = v0 * v0 + v1 * v1;
#pragma unroll
        for (int o2 = 32; o2 > 0; o2 >>= 1) {
            s  += __shfl_xor(s,  o2, 64);
            s2 += __shfl_xor(s2, o2, 64);
        }
        float mu = s * (1.0f / CDIM);
        float var = s2 * (1.0f / CDIM) - mu * mu;
        float rs = rsqrtf(var + 1e-5f);
        float o0 = fmaxf((v0 - mu) * rs * lw0 + lb0, 0.0f);
        float o1 = fmaxf((v1 - mu) * rs * lw1 + lb1, 0.0f);
        size_t oi = (size_t)row * CDIM;
        xnext[oi + lane] = o0;
        xnext[oi + lane + 64] = o1;
        if (xnext_bf) {
            xnext_bf[oi + lane] = f2bf(o0);
            xnext_bf[oi + lane + 64] = f2bf(o1);
        }
    }
}

extern "C" void kernel_launch(void* const* d_in, const int* in_sizes, int n_in,
                              void* d_out, int out_size, void* d_ws, size_t ws_size,
                              hipStream_t stream)
{
    const float* x_a      = (const float*)d_in[0];
    const float* x_b      = (const float*)d_in[1];
    const float* schema_x = (const float*)d_in[2];
    const int*   e_ab     = (const int*)d_in[3];
    const int*   e_ba     = (const int*)d_in[4];
    const int*   e_aa     = (const int*)d_in[5];
    const int*   sei      = (const int*)d_in[6];
    const float* preW     = (const float*)d_in[7];
    const float* preb     = (const float*)d_in[8];
    const float* gcnW     = (const float*)d_in[9];
    const float* gcnb     = (const float*)d_in[10];
    const float* coW      = (const float*)d_in[11];
    const float* cob      = (const float*)d_in[12];
    const float* bases    = (const float*)d_in[13];
    const float* sbias    = (const float*)d_in[14];
    const float* lnw      = (const float*)d_in[15];
    const float* lnb      = (const float*)d_in[16];

    float* out     = (float*)d_out;
    float* out_xa  = out;
    float* out_xb  = out + 6400000;
    float* out_sf  = out + 12800000;
    float* out_ori = out + 12800512;

    float* ws = (float*)d_ws;
    int*      col    = (int*)ws;
    int*      rowptr = (int*)(ws + 2400000);
    unsigned* buf    = (unsigned*)(ws + 2550016);
    int*      bcnt   = (int*)(ws + 4950016);
    int*      boff   = (int*)(ws + 4950320);
    int*      bcur   = (int*)(ws + 4950624);
    float* xa_buf = ws + 4950928;
    float* xb_buf = ws + 11350928;
    float* Wbuf   = ws + 17750928;
    float* coeffs = ws + 17849232;
    unsigned short* xa_bf0 = (unsigned short*)(ws + 17849264);
    unsigned short* xb_bf0 = (unsigned short*)(ws + 21049328);
    unsigned short* xa_bf1 = (unsigned short*)(ws + 24249392);
    unsigned short* xb_bf1 = (unsigned short*)(ws + 27449456);

    schema_kernel<<<1, 512, 0, stream>>>(schema_x, sei, preW, preb, gcnW, gcnb,
                                         coW, cob, out_sf, out_ori, coeffs);
    build_w_kernel<<<384, 256, 0, stream>>>(bases, coeffs, Wbuf);

    tobf16_kernel<<<(NA * CDIM / 4 + 255) / 256, 256, 0, stream>>>(x_a, xa_bf0, NA * CDIM);
    tobf16_kernel<<<(NB * CDIM / 4 + 255) / 256, 256, 0, stream>>>(x_b, xb_bf0, NB * CDIM);
    zero_rows_kernel<<<1, 256, 0, stream>>>(xa_bf0, xb_bf0, xa_bf1, xb_bf1);

    // locality-aware CSR build
    hipMemsetAsync(bcnt, 0, 3 * NBUCK * sizeof(int), stream);
    dim3 cgrid((EDGES + 4095) / 4096, 3);
    bucket_count_kernel<<<cgrid, 256, 0, stream>>>(e_ab, e_ba, e_aa, bcnt);
    bucket_scan_kernel<<<1, 32, 0, stream>>>(bcnt, boff, bcur);
    bucket_partition_kernel<<<cgrid, 256, 0, stream>>>(e_ab, e_ba, e_aa, bcur, buf);
    dim3 sgrid(NBUCK, 3);
    bucket_scatter_kernel<<<sgrid, 256, 0, stream>>>(buf, boff, rowptr, col);

    const int* rp_ab = rowptr;
    const int* rp_ba = rowptr + (NN + 1);
    const int* rp_aa = rowptr + 2 * (NN + 1);
    const int* col_ab = col;
    const int* col_ba = col + EDGES;
    const int* col_aa = col + 2 * EDGES;

    for (int l = 0; l < 2; l++) {
        const float* xa_cur = (l == 0) ? x_a : xa_buf;
        const float* xb_cur = (l == 0) ? x_b : xb_buf;
        const unsigned short* xa_bf = (l == 0) ? xa_bf0 : xa_bf1;
        const unsigned short* xb_bf = (l == 0) ? xb_bf0 : xb_bf1;
        const float* Wab = Wbuf + (size_t)(l * 3 + 0) * 16384;
        const float* Wba = Wbuf + (size_t)(l * 3 + 1) * 16384;
        const float* Waa = Wbuf + (size_t)(l * 3 + 2) * 16384;
        float* xa_nxt = (l == 0) ? xa_buf : out_xa;
        float* xb_nxt = (l == 0) ? xb_buf : out_xb;
        unsigned short* xa_nbf = (l == 0) ? xa_bf1 : nullptr;
        unsigned short* xb_nbf = (l == 0) ? xb_bf1 : nullptr;

        fuse_b_kernel<<<NB / 8, 128, 0, stream>>>(
            xa_bf, xb_cur, rp_ab, col_ab, Wab,
            sbias + (size_t)(l * 3 + 0) * 128,
            lnw + (size_t)(l * 2 + 1) * 128, lnb + (size_t)(l * 2 + 1) * 128,
            xb_nxt, xb_nbf);
        fuse_a_kernel<<<NA / 8, 128, 0, stream>>>(
            xb_bf, rp_ba, col_ba, xa_bf, rp_aa, col_aa, xa_cur,
            Wba, Waa,
            sbias + (size_t)(l * 3 + 1) * 128, sbias + (size_t)(l * 3 + 2) * 128,
            lnw + (size_t)(l * 2 + 0) * 128, lnb + (size_t)(l * 2 + 0) * 128,
            xa_nxt, xa_nbf);
    }
}

// Round 8
// 558.181 us; speedup vs baseline: 4.6912x; 1.1776x over previous
//
#include <hip/hip_runtime.h>

#define NA 50000
#define NB 50000
#define NN 50000
#define CDIM 128
#define EDGES 800000
#define SS 8
#define INDIM 64
#define HDIM 64
#define NBASES 8
#define NBUCK 98
#define BSH 9

typedef __attribute__((ext_vector_type(8))) short bf16x8;
typedef __attribute__((ext_vector_type(4))) float f32x4;

// ---------------------------------------------------------------------------
// Workspace layout (4-byte element offsets):
//   0         col      [3*E]        int
//   2400000   rowptr   [3*(NN+1)]   int
//   2550016   buf      [3*E]        uint
//   4950016   bcnt     [3*98]       int      (pad 304)
//   4950320   boff     [3*99]       int      (pad 304)
//   4950624   bcur     [3*98]       int      (pad 304)
//   4950928   xa_buf   [NA*128]     float
//   11350928  xb_buf   [NB*128]     float
//   17750928  Wbf      ushort[6*128*128]  (bf16, row-major [j][k])
//   17800080  coeffs   [3*8]        float  (pad to 17800112)
//   17800112  xa_bf0   ushort[(NN+1)*128]   (row NN = zero row)
//   21000176  xb_bf0   ushort[(NN+1)*128]
//   24200240  xa_bf1   ushort[(NN+1)*128]
//   27400304  xb_bf1   ushort[(NN+1)*128]
//   30600368  end (~122 MB)
// ---------------------------------------------------------------------------

__device__ __forceinline__ unsigned short f2bf(float f) {
    unsigned u = __float_as_uint(f);
    return (unsigned short)((u + 0x7FFFu + ((u >> 16) & 1u)) >> 16);
}

// Schema GCN + coefficient computation. One block, 512 threads.
__global__ __launch_bounds__(512) void schema_kernel(
    const float* __restrict__ schema_x, const int* __restrict__ sei,
    const float* __restrict__ preW, const float* __restrict__ preb,
    const float* __restrict__ gcnW, const float* __restrict__ gcnb,
    const float* __restrict__ coW, const float* __restrict__ cob,
    float* __restrict__ out_sf, float* __restrict__ out_ori,
    float* __restrict__ coeffs)
{
    __shared__ float h[SS][HDIM];
    __shared__ float xw[SS][HDIM];
    __shared__ float sf[SS][HDIM];
    __shared__ float deg[SS];
    __shared__ float nrm[32];
    __shared__ int es[32], ed[32];

    int t = threadIdx.x;
    int i = t >> 6, j = t & 63;

    float acc = preb[j];
    for (int k = 0; k < INDIM; k++) acc += schema_x[i * INDIM + k] * preW[j * INDIM + k];
    h[i][j] = acc;
    out_ori[i * HDIM + j] = acc;
    if (t < SS) deg[t] = 0.0f;
    __syncthreads();

    if (t < 32) {
        int s, d;
        if (t < 24) { s = sei[t]; d = sei[24 + t]; }
        else        { s = t - 24; d = t - 24; }
        es[t] = s; ed[t] = d;
        atomicAdd(&deg[d], 1.0f);
    }
    __syncthreads();
    if (t < 32) {
        nrm[t] = rsqrtf(fmaxf(deg[es[t]], 1e-12f)) * rsqrtf(fmaxf(deg[ed[t]], 1e-12f));
    }
    float a2 = 0.0f;
    for (int k = 0; k < HDIM; k++) a2 += h[i][k] * gcnW[j * HDIM + k];
    xw[i][j] = a2;
    __syncthreads();

    float o = gcnb[j];
    for (int e = 0; e < 32; e++) {
        if (ed[e] == i) o += xw[es[e]][j] * nrm[e];
    }
    float s = fmaxf(o, 0.0f);
    sf[i][j] = s;
    out_sf[i * HDIM + j] = s;
    __syncthreads();

    if (t < 24) {
        int ty = t >> 3, ii = t & 7;
        int srow = (ty == 1) ? 1 : 0;
        int drow = (ty == 0) ? 1 : 0;
        float a = cob[ii];
        for (int k = 0; k < HDIM; k++) a += sf[srow][k] * coW[ii * (2 * HDIM) + k];
        for (int k = 0; k < HDIM; k++) a += sf[drow][k] * coW[ii * (2 * HDIM) + HDIM + k];
        coeffs[ty * 8 + ii] = a;
    }
}

// W in bf16, row-major [mat][j][k] (B-operand needs contiguous k per row)
__global__ __launch_bounds__(256) void build_w_kernel(
    const float* __restrict__ bases, const float* __restrict__ coeffs,
    unsigned short* __restrict__ Wbf)
{
    int idx = blockIdx.x * blockDim.x + threadIdx.x;   // < 6*16384
    int lt = idx >> 14;
    int jk = idx & 16383;
    int l = lt / 3, ty = lt % 3;
    float acc = 0.0f;
#pragma unroll
    for (int i = 0; i < NBASES; i++)
        acc += coeffs[ty * 8 + i] * bases[((size_t)(l * NBASES + i) << 14) + jk];
    Wbf[idx] = f2bf(acc);
}

__global__ __launch_bounds__(256) void tobf16_kernel(
    const float* __restrict__ in, unsigned short* __restrict__ out, int n)
{
    int i = (blockIdx.x * 256 + threadIdx.x) * 4;
    if (i >= n) return;
    float4 f = *(const float4*)(in + i);
    ushort4 o;
    o.x = f2bf(f.x); o.y = f2bf(f.y); o.z = f2bf(f.z); o.w = f2bf(f.w);
    *(ushort4*)(out + i) = o;
}

__global__ __launch_bounds__(256) void zero_rows_kernel(
    unsigned short* a0, unsigned short* b0, unsigned short* a1, unsigned short* b1)
{
    int t = threadIdx.x;
    int tab = t >> 6, w = t & 63;
    unsigned short* p = (tab == 0) ? a0 : (tab == 1) ? b0 : (tab == 2) ? a1 : b1;
    ((unsigned*)(p + (size_t)NN * CDIM))[w] = 0u;
}

// ---------------- locality-aware CSR build ----------------------------------

__global__ __launch_bounds__(256) void bucket_count_kernel(
    const int* __restrict__ ab, const int* __restrict__ ba,
    const int* __restrict__ aa, int* __restrict__ bcnt)
{
    __shared__ int h[NBUCK];
    int t = threadIdx.x;
    int ty = blockIdx.y;
    const int* ei = (ty == 0) ? ab : (ty == 1) ? ba : aa;
    if (t < NBUCK) h[t] = 0;
    __syncthreads();
    int cb = blockIdx.x * 4096;
    int en = min(cb + 4096, EDGES);
    for (int e = cb + t; e < en; e += 256)
        atomicAdd(&h[ei[EDGES + e] >> BSH], 1);
    __syncthreads();
    if (t < NBUCK) atomicAdd(&bcnt[ty * NBUCK + t], h[t]);
}

__global__ __launch_bounds__(32) void bucket_scan_kernel(
    const int* __restrict__ bcnt, int* __restrict__ boff, int* __restrict__ bcur)
{
    int t = threadIdx.x;
    if (t < 3) {
        int run = 0;
        for (int i = 0; i < NBUCK; i++) {
            int c = bcnt[t * NBUCK + i];
            boff[t * (NBUCK + 1) + i] = run;
            bcur[t * NBUCK + i] = run;
            run += c;
        }
        boff[t * (NBUCK + 1) + NBUCK] = run;
    }
}

__global__ __launch_bounds__(256) void bucket_partition_kernel(
    const int* __restrict__ ab, const int* __restrict__ ba,
    const int* __restrict__ aa, int* __restrict__ bcur,
    unsigned* __restrict__ buf)
{
    __shared__ int h[NBUCK];
    __shared__ int basearr[NBUCK];
    __shared__ int cur[NBUCK];
    int t = threadIdx.x;
    int ty = blockIdx.y;
    const int* ei = (ty == 0) ? ab : (ty == 1) ? ba : aa;
    if (t < NBUCK) h[t] = 0;
    __syncthreads();
    int cb = blockIdx.x * 4096;
    int en = min(cb + 4096, EDGES);
    for (int e = cb + t; e < en; e += 256)
        atomicAdd(&h[ei[EDGES + e] >> BSH], 1);
    __syncthreads();
    if (t < NBUCK) {
        basearr[t] = atomicAdd(&bcur[ty * NBUCK + t], h[t]);
        cur[t] = 0;
    }
    __syncthreads();
    for (int e = cb + t; e < en; e += 256) {
        int src = ei[e], dst = ei[EDGES + e];
        int b = dst >> BSH;
        int r = atomicAdd(&cur[b], 1);
        buf[(size_t)ty * EDGES + basearr[b] + r] =
            ((unsigned)(dst & 511) << 16) | (unsigned)src;
    }
}

__global__ __launch_bounds__(256) void bucket_scatter_kernel(
    const unsigned* __restrict__ buf, const int* __restrict__ boff,
    int* __restrict__ rowptr, int* __restrict__ col)
{
    __shared__ int cnt[512];
    __shared__ int part[256];
    int t = threadIdx.x;
    int b = blockIdx.x, ty = blockIdx.y;
    int nstart = boff[ty * (NBUCK + 1) + b];
    int nend   = boff[ty * (NBUCK + 1) + b + 1];
    int n = nend - nstart;
    cnt[t] = 0; cnt[t + 256] = 0;
    __syncthreads();
    const unsigned* bb = buf + (size_t)ty * EDGES + nstart;
    for (int i = t; i < n; i += 256)
        atomicAdd(&cnt[bb[i] >> 16], 1);
    __syncthreads();
    int a0 = cnt[2 * t], a1 = cnt[2 * t + 1];
    int s = a0 + a1;
    part[t] = s;
    __syncthreads();
    for (int off = 1; off < 256; off <<= 1) {
        int v = (t >= off) ? part[t - off] : 0;
        __syncthreads();
        part[t] += v;
        __syncthreads();
    }
    int excl = part[t] - s;
    int p0 = excl, p1 = excl + a0;
    cnt[2 * t] = p0; cnt[2 * t + 1] = p1;
    int row0 = (b << BSH) + 2 * t;
    int rbase = ty * (NN + 1);
    if (row0 < NN)     rowptr[rbase + row0] = nstart + p0;
    if (row0 + 1 < NN) rowptr[rbase + row0 + 1] = nstart + p1;
    if (b == NBUCK - 1 && t == 255) rowptr[rbase + NN] = EDGES;
    __syncthreads();
    int* cc = col + (size_t)ty * EDGES + nstart;
    for (int i = t; i < n; i += 256) {
        unsigned pk = bb[i];
        int r = atomicAdd(&cnt[pk >> 16], 1);
        cc[r] = (int)(pk & 0xFFFFu);
    }
}

// ---------------- fused gather + MFMA matmul + LN -> ReLU -------------------

__device__ __forceinline__ float4 gather2_bf(
    const unsigned short* __restrict__ xsrc, const int* __restrict__ col,
    int s, int e, int half, int off)
{
    float4 g = {0.f, 0.f, 0.f, 0.f};
    int n = e - s;
    if (n > 0) {
        int cs[16];
#pragma unroll
        for (int j = 0; j < 16; j++) {
            int slot = s + 2 * j + half;
            int cc = col[min(slot, e - 1)];
            cs[j] = (slot < e) ? cc : NN;
        }
        uint2 v[16];
#pragma unroll
        for (int j = 0; j < 8; j++)
            v[j] = *(const uint2*)(xsrc + (size_t)cs[j] * CDIM + off);
        if (n > 16) {
#pragma unroll
            for (int j = 8; j < 16; j++)
                v[j] = *(const uint2*)(xsrc + (size_t)cs[j] * CDIM + off);
        } else {
#pragma unroll
            for (int j = 8; j < 16; j++) v[j] = make_uint2(0u, 0u);
        }
#pragma unroll
        for (int j = 0; j < 16; j++) {
            g.x += __uint_as_float(v[j].x << 16);
            g.y += __uint_as_float(v[j].x & 0xffff0000u);
            g.z += __uint_as_float(v[j].y << 16);
            g.w += __uint_as_float(v[j].y & 0xffff0000u);
        }
        for (int b2 = s + 32; b2 < e; b2 += 16) {
#pragma unroll
            for (int j = 0; j < 8; j++) {
                int slot = b2 + 2 * j + half;
                int cc = col[min(slot, e - 1)];
                int id = (slot < e) ? cc : NN;
                uint2 vv = *(const uint2*)(xsrc + (size_t)id * CDIM + off);
                g.x += __uint_as_float(vv.x << 16);
                g.y += __uint_as_float(vv.x & 0xffff0000u);
                g.z += __uint_as_float(vv.y << 16);
                g.w += __uint_as_float(vv.y & 0xffff0000u);
            }
        }
    }
    g.x += __shfl_xor(g.x, 32, 64);
    g.y += __shfl_xor(g.y, 32, 64);
    g.z += __shfl_xor(g.z, 32, 64);
    g.w += __shfl_xor(g.w, 32, 64);
    return g;
}

#define RROWS 32
#define USTR 136   // ushort stride (pad) for bf16 U/V tiles
#define SSTR 129   // float stride for acc staging

// b-side: mean(bf x_a) + x_b -> bf16 U; U @ W^T (MFMA) + bias -> LN -> ReLU
__global__ __launch_bounds__(256) void fuse_b_kernel(
    const unsigned short* __restrict__ xsrc, const float* __restrict__ xdst,
    const int* __restrict__ rowptr, const int* __restrict__ col,
    const unsigned short* __restrict__ Wbf, const float* __restrict__ bias,
    const float* __restrict__ lnw, const float* __restrict__ lnb,
    float* __restrict__ xnext, unsigned short* __restrict__ xnext_bf)
{
    __shared__ unsigned short Ubf[RROWS * USTR];
    __shared__ float stage[RROWS * SSTR];
    int t = threadIdx.x;
    int base = blockIdx.x * RROWS;
    int wv = t >> 6;
    int lane = t & 63;
    int half = lane >> 5, cl = lane & 31;
    int off = cl << 2;

    for (int rr = 0; rr < RROWS / 4; rr++) {
        int r = rr * 4 + wv;
        int row = base + r;
        if (row < NN) {
            int s = rowptr[row], e = rowptr[row + 1];
            float4 g = gather2_bf(xsrc, col, s, e, half, off);
            if (half == 0) {
                float inv = 1.0f / (float)max(e - s, 1);
                const float4 xv = *(const float4*)(xdst + (size_t)row * CDIM + off);
                ushort4 o;
                o.x = f2bf(g.x * inv + xv.x);
                o.y = f2bf(g.y * inv + xv.y);
                o.z = f2bf(g.z * inv + xv.z);
                o.w = f2bf(g.w * inv + xv.w);
                *(ushort4*)&Ubf[r * USTR + off] = o;
            }
        } else if (half == 0) {
            *(ushort4*)&Ubf[r * USTR + off] = make_ushort4(0, 0, 0, 0);
        }
    }
    __syncthreads();

    // MFMA: wave wv -> N-tiles {2wv, 2wv+1}, M-tiles {0,1}
    int qd = lane >> 4;
    int ln16 = lane & 15;
    f32x4 acc00 = {0.f,0.f,0.f,0.f}, acc01 = acc00, acc10 = acc00, acc11 = acc00;
#pragma unroll
    for (int ks = 0; ks < 4; ks++) {
        int koff = ks * 32 + qd * 8;
        bf16x8 a0 = *(const bf16x8*)&Ubf[(ln16) * USTR + koff];
        bf16x8 a1 = *(const bf16x8*)&Ubf[(16 + ln16) * USTR + koff];
        bf16x8 b0 = *(const bf16x8*)&Wbf[(size_t)((2 * wv + 0) * 16 + ln16) * CDIM + koff];
        bf16x8 b1 = *(const bf16x8*)&Wbf[(size_t)((2 * wv + 1) * 16 + ln16) * CDIM + koff];
        acc00 = __builtin_amdgcn_mfma_f32_16x16x32_bf16(a0, b0, acc00, 0, 0, 0);
        acc01 = __builtin_amdgcn_mfma_f32_16x16x32_bf16(a0, b1, acc01, 0, 0, 0);
        acc10 = __builtin_amdgcn_mfma_f32_16x16x32_bf16(a1, b0, acc10, 0, 0, 0);
        acc11 = __builtin_amdgcn_mfma_f32_16x16x32_bf16(a1, b1, acc11, 0, 0, 0);
    }
    // C/D layout: col = lane&15 (in tile), row = quad*4 + reg
    {
        int c0 = (2 * wv + 0) * 16 + ln16;
        int c1 = (2 * wv + 1) * 16 + ln16;
#pragma unroll
        for (int i = 0; i < 4; i++) {
            int r0 = qd * 4 + i;
            stage[r0 * SSTR + c0] = acc00[i];
            stage[r0 * SSTR + c1] = acc01[i];
            stage[(16 + r0) * SSTR + c0] = acc10[i];
            stage[(16 + r0) * SSTR + c1] = acc11[i];
        }
    }
    __syncthreads();

    float b0v = bias[lane], b1v = bias[lane + 64];
    float lw0 = lnw[lane], lw1 = lnw[lane + 64];
    float lb0 = lnb[lane], lb1 = lnb[lane + 64];
    for (int rr = 0; rr < RROWS / 4; rr++) {
        int r = rr * 4 + wv;
        int row = base + r;
        if (row >= NN) continue;
        float v0 = stage[r * SSTR + lane] + b0v;
        float v1 = stage[r * SSTR + lane + 64] + b1v;
        float s = v0 + v1, s2 = v0 * v0 + v1 * v1;
#pragma unroll
        for (int o2 = 32; o2 > 0; o2 >>= 1) {
            s  += __shfl_xor(s,  o2, 64);
            s2 += __shfl_xor(s2, o2, 64);
        }
        float mu = s * (1.0f / CDIM);
        float var = s2 * (1.0f / CDIM) - mu * mu;
        float rs = rsqrtf(var + 1e-5f);
        float o0 = fmaxf((v0 - mu) * rs * lw0 + lb0, 0.0f);
        float o1 = fmaxf((v1 - mu) * rs * lw1 + lb1, 0.0f);
        size_t oi = (size_t)row * CDIM;
        xnext[oi + lane] = o0;
        xnext[oi + lane + 64] = o1;
        if (xnext_bf) {
            xnext_bf[oi + lane] = f2bf(o0);
            xnext_bf[oi + lane + 64] = f2bf(o1);
        }
    }
}

// a-side: U = mean_ba(bf x_b)+x_a, V = mean_aa(bf x_a)+x_a;
// out = U@W1^T + V@W2^T + b1 + b2 (MFMA) -> LN -> ReLU
__global__ __launch_bounds__(256) void fuse_a_kernel(
    const unsigned short* __restrict__ xsrc1, const int* __restrict__ rowptr1, const int* __restrict__ col1,
    const unsigned short* __restrict__ xsrc2, const int* __restrict__ rowptr2, const int* __restrict__ col2,
    const float* __restrict__ xdst,
    const unsigned short* __restrict__ W1bf, const unsigned short* __restrict__ W2bf,
    const float* __restrict__ bias1, const float* __restrict__ bias2,
    const float* __restrict__ lnw, const float* __restrict__ lnb,
    float* __restrict__ xnext, unsigned short* __restrict__ xnext_bf)
{
    __shared__ unsigned short Ubf[RROWS * USTR];
    __shared__ unsigned short Vbf[RROWS * USTR];
    __shared__ float stage[RROWS * SSTR];
    int t = threadIdx.x;
    int base = blockIdx.x * RROWS;
    int wv = t >> 6;
    int lane = t & 63;
    int half = lane >> 5, cl = lane & 31;
    int off = cl << 2;

    for (int rr = 0; rr < RROWS / 4; rr++) {
        int r = rr * 4 + wv;
        int row = base + r;
        if (row < NN) {
            int s1 = rowptr1[row], e1 = rowptr1[row + 1];
            float4 g1 = gather2_bf(xsrc1, col1, s1, e1, half, off);
            int s2 = rowptr2[row], e2 = rowptr2[row + 1];
            float4 g2 = gather2_bf(xsrc2, col2, s2, e2, half, off);
            if (half == 0) {
                const float4 xv = *(const float4*)(xdst + (size_t)row * CDIM + off);
                float i1 = 1.0f / (float)max(e1 - s1, 1);
                float i2 = 1.0f / (float)max(e2 - s2, 1);
                ushort4 ou, ov;
                ou.x = f2bf(g1.x * i1 + xv.x); ou.y = f2bf(g1.y * i1 + xv.y);
                ou.z = f2bf(g1.z * i1 + xv.z); ou.w = f2bf(g1.w * i1 + xv.w);
                ov.x = f2bf(g2.x * i2 + xv.x); ov.y = f2bf(g2.y * i2 + xv.y);
                ov.z = f2bf(g2.z * i2 + xv.z); ov.w = f2bf(g2.w * i2 + xv.w);
                *(ushort4*)&Ubf[r * USTR + off] = ou;
                *(ushort4*)&Vbf[r * USTR + off] = ov;
            }
        } else if (half == 0) {
            *(ushort4*)&Ubf[r * USTR + off] = make_ushort4(0, 0, 0, 0);
            *(ushort4*)&Vbf[r * USTR + off] = make_ushort4(0, 0, 0, 0);
        }
    }
    __syncthreads();

    int qd = lane >> 4;
    int ln16 = lane & 15;
    f32x4 acc00 = {0.f,0.f,0.f,0.f}, acc01 = acc00, acc10 = acc00, acc11 = acc00;
#pragma unroll
    for (int ks = 0; ks < 4; ks++) {
        int koff = ks * 32 + qd * 8;
        bf16x8 aU0 = *(const bf16x8*)&Ubf[(ln16) * USTR + koff];
        bf16x8 aU1 = *(const bf16x8*)&Ubf[(16 + ln16) * USTR + koff];
        bf16x8 aV0 = *(const bf16x8*)&Vbf[(ln16) * USTR + koff];
        bf16x8 aV1 = *(const bf16x8*)&Vbf[(16 + ln16) * USTR + koff];
        size_t wrow0 = (size_t)((2 * wv + 0) * 16 + ln16) * CDIM + koff;
        size_t wrow1 = (size_t)((2 * wv + 1) * 16 + ln16) * CDIM + koff;
        bf16x8 b10 = *(const bf16x8*)&W1bf[wrow0];
        bf16x8 b11 = *(const bf16x8*)&W1bf[wrow1];
        bf16x8 b20 = *(const bf16x8*)&W2bf[wrow0];
        bf16x8 b21 = *(const bf16x8*)&W2bf[wrow1];
        acc00 = __builtin_amdgcn_mfma_f32_16x16x32_bf16(aU0, b10, acc00, 0, 0, 0);
        acc01 = __builtin_amdgcn_mfma_f32_16x16x32_bf16(aU0, b11, acc01, 0, 0, 0);
        acc10 = __builtin_amdgcn_mfma_f32_16x16x32_bf16(aU1, b10, acc10, 0, 0, 0);
        acc11 = __builtin_amdgcn_mfma_f32_16x16x32_bf16(aU1, b11, acc11, 0, 0, 0);
        acc00 = __builtin_amdgcn_mfma_f32_16x16x32_bf16(aV0, b20, acc00, 0, 0, 0);
        acc01 = __builtin_amdgcn_mfma_f32_16x16x32_bf16(aV0, b21, acc01, 0, 0, 0);
        acc10 = __builtin_amdgcn_mfma_f32_16x16x32_bf16(aV1, b20, acc10, 0, 0, 0);
        acc11 = __builtin_amdgcn_mfma_f32_16x16x32_bf16(aV1, b21, acc11, 0, 0, 0);
    }
    {
        int c0 = (2 * wv + 0) * 16 + ln16;
        int c1 = (2 * wv + 1) * 16 + ln16;
#pragma unroll
        for (int i = 0; i < 4; i++) {
            int r0 = qd * 4 + i;
            stage[r0 * SSTR + c0] = acc00[i];
            stage[r0 * SSTR + c1] = acc01[i];
            stage[(16 + r0) * SSTR + c0] = acc10[i];
            stage[(16 + r0) * SSTR + c1] = acc11[i];
        }
    }
    __syncthreads();

    float b0v = bias1[lane] + bias2[lane];
    float b1v = bias1[lane + 64] + bias2[lane + 64];
    float lw0 = lnw[lane], lw1 = lnw[lane + 64];
    float lb0 = lnb[lane], lb1 = lnb[lane + 64];
    for (int rr = 0; rr < RROWS / 4; rr++) {
        int r = rr * 4 + wv;
        int row = base + r;
        if (row >= NN) continue;
        float v0 = stage[r * SSTR + lane] + b0v;
        float v1 = stage[r * SSTR + lane + 64] + b1v;
        float s = v0 + v1, s2 = v0 * v0 + v1 * v1;
#pragma unroll
        for (int o2 = 32; o2 > 0; o2 >>= 1) {
            s  += __shfl_xor(s,  o2, 64);
            s2 += __shfl_xor(s2, o2, 64);
        }
        float mu = s * (1.0f / CDIM);
        float var = s2 * (1.0f / CDIM) - mu * mu;
        float rs = rsqrtf(var + 1e-5f);
        float o0 = fmaxf((v0 - mu) * rs * lw0 + lb0, 0.0f);
        float o1 = fmaxf((v1 - mu) * rs * lw1 + lb1, 0.0f);
        size_t oi = (size_t)row * CDIM;
        xnext[oi + lane] = o0;
        xnext[oi + lane + 64] = o1;
        if (xnext_bf) {
            xnext_bf[oi + lane] = f2bf(o0);
            xnext_bf[oi + lane + 64] = f2bf(o1);
        }
    }
}

extern "C" void kernel_launch(void* const* d_in, const int* in_sizes, int n_in,
                              void* d_out, int out_size, void* d_ws, size_t ws_size,
                              hipStream_t stream)
{
    const float* x_a      = (const float*)d_in[0];
    const float* x_b      = (const float*)d_in[1];
    const float* schema_x = (const float*)d_in[2];
    const int*   e_ab     = (const int*)d_in[3];
    const int*   e_ba     = (const int*)d_in[4];
    const int*   e_aa     = (const int*)d_in[5];
    const int*   sei      = (const int*)d_in[6];
    const float* preW     = (const float*)d_in[7];
    const float* preb     = (const float*)d_in[8];
    const float* gcnW     = (const float*)d_in[9];
    const float* gcnb     = (const float*)d_in[10];
    const float* coW      = (const float*)d_in[11];
    const float* cob      = (const float*)d_in[12];
    const float* bases    = (const float*)d_in[13];
    const float* sbias    = (const float*)d_in[14];
    const float* lnw      = (const float*)d_in[15];
    const float* lnb      = (const float*)d_in[16];

    float* out     = (float*)d_out;
    float* out_xa  = out;
    float* out_xb  = out + 6400000;
    float* out_sf  = out + 12800000;
    float* out_ori = out + 12800512;

    float* ws = (float*)d_ws;
    int*      col    = (int*)ws;
    int*      rowptr = (int*)(ws + 2400000);
    unsigned* buf    = (unsigned*)(ws + 2550016);
    int*      bcnt   = (int*)(ws + 4950016);
    int*      boff   = (int*)(ws + 4950320);
    int*      bcur   = (int*)(ws + 4950624);
    float* xa_buf = ws + 4950928;
    float* xb_buf = ws + 11350928;
    unsigned short* Wbf = (unsigned short*)(ws + 17750928);
    float* coeffs = ws + 17800080;
    unsigned short* xa_bf0 = (unsigned short*)(ws + 17800112);
    unsigned short* xb_bf0 = (unsigned short*)(ws + 21000176);
    unsigned short* xa_bf1 = (unsigned short*)(ws + 24200240);
    unsigned short* xb_bf1 = (unsigned short*)(ws + 27400304);

    schema_kernel<<<1, 512, 0, stream>>>(schema_x, sei, preW, preb, gcnW, gcnb,
                                         coW, cob, out_sf, out_ori, coeffs);
    build_w_kernel<<<384, 256, 0, stream>>>(bases, coeffs, Wbf);

    tobf16_kernel<<<(NA * CDIM / 4 + 255) / 256, 256, 0, stream>>>(x_a, xa_bf0, NA * CDIM);
    tobf16_kernel<<<(NB * CDIM / 4 + 255) / 256, 256, 0, stream>>>(x_b, xb_bf0, NB * CDIM);
    zero_rows_kernel<<<1, 256, 0, stream>>>(xa_bf0, xb_bf0, xa_bf1, xb_bf1);

    hipMemsetAsync(bcnt, 0, 3 * NBUCK * sizeof(int), stream);
    dim3 cgrid((EDGES + 4095) / 4096, 3);
    bucket_count_kernel<<<cgrid, 256, 0, stream>>>(e_ab, e_ba, e_aa, bcnt);
    bucket_scan_kernel<<<1, 32, 0, stream>>>(bcnt, boff, bcur);
    bucket_partition_kernel<<<cgrid, 256, 0, stream>>>(e_ab, e_ba, e_aa, bcur, buf);
    dim3 sgrid(NBUCK, 3);
    bucket_scatter_kernel<<<sgrid, 256, 0, stream>>>(buf, boff, rowptr, col);

    const int* rp_ab = rowptr;
    const int* rp_ba = rowptr + (NN + 1);
    const int* rp_aa = rowptr + 2 * (NN + 1);
    const int* col_ab = col;
    const int* col_ba = col + EDGES;
    const int* col_aa = col + 2 * EDGES;

    const int fgrid = (NN + RROWS - 1) / RROWS;   // 1563

    for (int l = 0; l < 2; l++) {
        const float* xa_cur = (l == 0) ? x_a : xa_buf;
        const float* xb_cur = (l == 0) ? x_b : xb_buf;
        const unsigned short* xa_bf = (l == 0) ? xa_bf0 : xa_bf1;
        const unsigned short* xb_bf = (l == 0) ? xb_bf0 : xb_bf1;
        const unsigned short* Wab = Wbf + (size_t)(l * 3 + 0) * 16384;
        const unsigned short* Wba = Wbf + (size_t)(l * 3 + 1) * 16384;
        const unsigned short* Waa = Wbf + (size_t)(l * 3 + 2) * 16384;
        float* xa_nxt = (l == 0) ? xa_buf : out_xa;
        float* xb_nxt = (l == 0) ? xb_buf : out_xb;
        unsigned short* xa_nbf = (l == 0) ? xa_bf1 : nullptr;
        unsigned short* xb_nbf = (l == 0) ? xb_bf1 : nullptr;

        fuse_b_kernel<<<fgrid, 256, 0, stream>>>(
            xa_bf, xb_cur, rp_ab, col_ab, Wab,
            sbias + (size_t)(l * 3 + 0) * 128,
            lnw + (size_t)(l * 2 + 1) * 128, lnb + (size_t)(l * 2 + 1) * 128,
            xb_nxt, xb_nbf);
        fuse_a_kernel<<<fgrid, 256, 0, stream>>>(
            xb_bf, rp_ba, col_ba, xa_bf, rp_aa, col_aa, xa_cur,
            Wba, Waa,
            sbias + (size_t)(l * 3 + 1) * 128, sbias + (size_t)(l * 3 + 2) * 128,
            lnw + (size_t)(l * 2 + 0) * 128, lnb + (size_t)(l * 2 + 0) * 128,
            xa_nxt, xa_nbf);
    }
}